// Round 1
// baseline (2536.685 us; speedup 1.0000x reference)
//
#include <hip/hip_runtime.h>
#include <math.h>

#define N_NODES 50000
#define N_EDGES 800000
#define IN_FEAT 128
#define HIDDEN 256
#define NUM_GRAPHS 128
#define NUM_CLASSES 10
#define BN_EPS 1e-5f

// ---------------- CSR build ----------------
__global__ void k_count(const int* __restrict__ dst, int* __restrict__ cnt) {
    int e = blockIdx.x * 256 + threadIdx.x;
    if (e < N_EDGES) atomicAdd(&cnt[dst[e]], 1);
}

__global__ void k_count_batch(const int* __restrict__ batch, int* __restrict__ gcnt) {
    int v = blockIdx.x * 256 + threadIdx.x;
    if (v < N_NODES) atomicAdd(&gcnt[batch[v]], 1);
}

// single-block exclusive scan over per-node edge counts; also emits dinv
__global__ void k_scan(const int* __restrict__ cnt, int* __restrict__ row_ptr,
                       int* __restrict__ cursor, float* __restrict__ dinv) {
    __shared__ int part[512];
    int tid = threadIdx.x;                 // 512 threads
    const int CH = (N_NODES + 511) / 512;  // 98
    int lo = tid * CH, hi = min(lo + CH, N_NODES);
    int s = 0;
    for (int i = lo; i < hi; ++i) s += cnt[i];
    part[tid] = s;
    __syncthreads();
    if (tid == 0) {
        int run = 0;
        for (int i = 0; i < 512; ++i) { int t = part[i]; part[i] = run; run += t; }
        row_ptr[N_NODES] = run;
    }
    __syncthreads();
    int run = part[tid];
    for (int i = lo; i < hi; ++i) {
        row_ptr[i] = run;
        cursor[i]  = run;
        int c = cnt[i];
        run += c;
        dinv[i] = rsqrtf(1.0f + (float)c);   // self-loop included in degree
    }
}

__global__ void k_fill(const int* __restrict__ src, const int* __restrict__ dst,
                       int* __restrict__ cursor, int* __restrict__ col) {
    int e = blockIdx.x * 256 + threadIdx.x;
    if (e < N_EDGES) {
        int slot = atomicAdd(&cursor[dst[e]], 1);
        col[slot] = src[e];
    }
}

// ---------------- prescale: p0 = x * dinv[row] ----------------
__global__ void k_prescale(const float* __restrict__ x, const float* __restrict__ dinv,
                           float* __restrict__ p0) {
    int i = blockIdx.x * 256 + threadIdx.x;      // over N*IN_FEAT/4 float4s
    if (i < N_NODES * IN_FEAT / 4) {
        float4 v = ((const float4*)x)[i];
        float d = dinv[i / (IN_FEAT / 4)];
        v.x *= d; v.y *= d; v.z *= d; v.w *= d;
        ((float4*)p0)[i] = v;
    }
}

// ---------------- aggregation: out[v] = dinv[v] * (p[v] + sum p[col]) ----------------
// wave per node, lane handles one float4 of the feature row
template <int F>
__global__ __launch_bounds__(256) void k_agg(const float* __restrict__ p,
                                             const int* __restrict__ col,
                                             const int* __restrict__ row_ptr,
                                             const float* __restrict__ dinv,
                                             float* __restrict__ out) {
    int wave = threadIdx.x >> 6;
    int lane = threadIdx.x & 63;
    int v = blockIdx.x * 4 + wave;
    if (v >= N_NODES) return;
    const int LPF = F / 4;              // float4 slots per row (32 or 64)
    if (lane >= LPF) return;
    float4 acc = ((const float4*)(p + (size_t)v * F))[lane];
    int rp0 = row_ptr[v], rp1 = row_ptr[v + 1];
    for (int i = rp0; i < rp1; ++i) {
        int s = col[i];
        float4 q = ((const float4*)(p + (size_t)s * F))[lane];
        acc.x += q.x; acc.y += q.y; acc.z += q.z; acc.w += q.w;
    }
    float d = dinv[v];
    acc.x *= d; acc.y *= d; acc.z *= d; acc.w *= d;
    ((float4*)(out + (size_t)v * F))[lane] = acc;
}

// ---------------- GEMM: out = epi(A @ W + bias) ----------------
// EPI: 0 = BN+relu then *dinv ; 1 = relu then *dinv ; 2 = relu (plain)
template <int KDIM, int EPI>
__global__ __launch_bounds__(256) void k_gemm(const float* __restrict__ A,
                                              const float* __restrict__ W,
                                              const float* __restrict__ bias,
                                              const float* __restrict__ gamma,
                                              const float* __restrict__ beta,
                                              const float* __restrict__ mean,
                                              const float* __restrict__ var,
                                              const float* __restrict__ dinv,
                                              float* __restrict__ out) {
    __shared__ float As[16][65];
    __shared__ float Bs[16][256];
    int t = threadIdx.x;
    int v0 = blockIdx.x * 64;
    int cg = t & 63;     // cols cg*4 .. cg*4+3
    int rg = t >> 6;     // rows rg*16 .. rg*16+15
    float acc[16][4];
#pragma unroll
    for (int r = 0; r < 16; ++r)
#pragma unroll
        for (int c = 0; c < 4; ++c) acc[r][c] = 0.f;

    int arow = t >> 2;          // 0..63
    int akk  = (t & 3) * 4;     // 0,4,8,12
    for (int k0 = 0; k0 < KDIM; k0 += 16) {
        {
            int grow = v0 + arow;
            float4 av = make_float4(0.f, 0.f, 0.f, 0.f);
            if (grow < N_NODES) av = *(const float4*)(A + (size_t)grow * KDIM + k0 + akk);
            As[akk + 0][arow] = av.x; As[akk + 1][arow] = av.y;
            As[akk + 2][arow] = av.z; As[akk + 3][arow] = av.w;
        }
#pragma unroll
        for (int kk = 0; kk < 16; ++kk) Bs[kk][t] = W[(size_t)(k0 + kk) * HIDDEN + t];
        __syncthreads();
#pragma unroll
        for (int kk = 0; kk < 16; ++kk) {
            float4 b = *(const float4*)&Bs[kk][cg * 4];
#pragma unroll
            for (int r = 0; r < 16; ++r) {
                float a = As[kk][rg * 16 + r];
                acc[r][0] += a * b.x; acc[r][1] += a * b.y;
                acc[r][2] += a * b.z; acc[r][3] += a * b.w;
            }
        }
        __syncthreads();
    }
    int c0 = cg * 4;
    float bi[4], sc[4], sh[4];
#pragma unroll
    for (int j = 0; j < 4; ++j) {
        bi[j] = bias[c0 + j];
        if constexpr (EPI == 0) {
            float s = gamma[c0 + j] * rsqrtf(var[c0 + j] + BN_EPS);
            sc[j] = s; sh[j] = beta[c0 + j] - mean[c0 + j] * s;
        }
    }
#pragma unroll
    for (int r = 0; r < 16; ++r) {
        int grow = v0 + rg * 16 + r;
        if (grow < N_NODES) {
            float d = (EPI == 2) ? 1.f : dinv[grow];
            float o[4];
#pragma unroll
            for (int j = 0; j < 4; ++j) {
                float y = acc[r][j] + bi[j];
                if constexpr (EPI == 0) y = y * sc[j] + sh[j];
                y = fmaxf(y, 0.f);
                o[j] = y * d;
            }
            *(float4*)(out + (size_t)grow * HIDDEN + c0) = make_float4(o[0], o[1], o[2], o[3]);
        }
    }
}

// ---------------- head: mean-pool per graph + logits + log_softmax ----------------
__global__ __launch_bounds__(256) void k_head(const float* __restrict__ h,
                                              const int* __restrict__ batch,
                                              const int* __restrict__ gcnt,
                                              const float* __restrict__ W2,
                                              const float* __restrict__ b2,
                                              float* __restrict__ outp) {
    __shared__ float accs[4][HIDDEN];
    __shared__ float pooled[HIDDEN];
    int g = blockIdx.x;
    int wave = threadIdx.x >> 6, lane = threadIdx.x & 63;
    float4 acc = make_float4(0.f, 0.f, 0.f, 0.f);
    for (int v = wave; v < N_NODES; v += 4) {
        if (batch[v] == g) {
            float4 q = *(const float4*)(h + (size_t)v * HIDDEN + lane * 4);
            acc.x += q.x; acc.y += q.y; acc.z += q.z; acc.w += q.w;
        }
    }
    *(float4*)&accs[wave][lane * 4] = acc;
    __syncthreads();
    int t = threadIdx.x;
    float inv = 1.0f / fmaxf((float)gcnt[g], 1.0f);
    pooled[t] = (accs[0][t] + accs[1][t] + accs[2][t] + accs[3][t]) * inv;
    __syncthreads();
    if (t < 64) {
        float lg = -INFINITY;
        if (t < NUM_CLASSES) {
            lg = b2[t];
            for (int k = 0; k < HIDDEN; ++k) lg += pooled[k] * W2[k * NUM_CLASSES + t];
        }
        float m = lg;
        for (int off = 1; off < 16; off <<= 1) m = fmaxf(m, __shfl_xor(m, off));
        float e = (t < 16) ? expf(lg - m) : 0.f;
        float ssum = e;
        for (int off = 1; off < 16; off <<= 1) ssum += __shfl_xor(ssum, off);
        if (t < NUM_CLASSES) outp[g * NUM_CLASSES + t] = lg - m - logf(ssum);
    }
}

extern "C" void kernel_launch(void* const* d_in, const int* in_sizes, int n_in,
                              void* d_out, int out_size, void* d_ws, size_t ws_size,
                              hipStream_t stream) {
    const float* x     = (const float*)d_in[0];
    const int*   ei    = (const int*)d_in[1];
    const int*   batch = (const int*)d_in[2];
    const float* W1    = (const float*)d_in[3];
    const float* b1    = (const float*)d_in[4];
    const float* gamma = (const float*)d_in[5];
    const float* beta  = (const float*)d_in[6];
    const float* rmean = (const float*)d_in[7];
    const float* rvar  = (const float*)d_in[8];
    const float* Wsp   = (const float*)d_in[9];
    const float* bsp   = (const float*)d_in[10];
    const float* W2    = (const float*)d_in[11];
    const float* b2    = (const float*)d_in[12];
    float* out = (float*)d_out;

    char* w = (char*)d_ws;
    size_t off = 0;
    auto alloc = [&](size_t bytes) -> void* {
        void* p = w + off;
        off = (off + bytes + 255) & ~(size_t)255;
        return p;
    };
    int*   cnt    = (int*)alloc((size_t)N_NODES * 4);
    int*   gcnt   = (int*)alloc((size_t)NUM_GRAPHS * 4);
    int*   rowp   = (int*)alloc((size_t)(N_NODES + 1) * 4);
    int*   cursor = (int*)alloc((size_t)N_NODES * 4);
    int*   col    = (int*)alloc((size_t)N_EDGES * 4);
    float* dinv   = (float*)alloc((size_t)N_NODES * 4);
    float* bufA   = (float*)alloc((size_t)N_NODES * HIDDEN * 4);
    float* bufB   = (float*)alloc((size_t)N_NODES * HIDDEN * 4);

    hipMemsetAsync(cnt, 0, (size_t)N_NODES * 4, stream);
    hipMemsetAsync(gcnt, 0, (size_t)NUM_GRAPHS * 4, stream);

    const int* srcp = ei;
    const int* dstp = ei + N_EDGES;

    k_count<<<(N_EDGES + 255) / 256, 256, 0, stream>>>(dstp, cnt);
    k_count_batch<<<(N_NODES + 255) / 256, 256, 0, stream>>>(batch, gcnt);
    k_scan<<<1, 512, 0, stream>>>(cnt, rowp, cursor, dinv);
    k_fill<<<(N_EDGES + 255) / 256, 256, 0, stream>>>(srcp, dstp, cursor, col);

    // layer 1: p0 = x*dinv ; a0 = agg(p0) ; bufA = dinv*relu(bn(a0@W1+b1))
    k_prescale<<<(N_NODES * IN_FEAT / 4 + 255) / 256, 256, 0, stream>>>(x, dinv, bufA);
    k_agg<IN_FEAT><<<(N_NODES + 3) / 4, 256, 0, stream>>>(bufA, col, rowp, dinv, bufB);
    k_gemm<IN_FEAT, 0><<<(N_NODES + 63) / 64, 256, 0, stream>>>(
        bufB, W1, b1, gamma, beta, rmean, rvar, dinv, bufA);

    // layers 2..3: p = dinv*relu(a@W+b)
    k_agg<HIDDEN><<<(N_NODES + 3) / 4, 256, 0, stream>>>(bufA, col, rowp, dinv, bufB);
    k_gemm<HIDDEN, 1><<<(N_NODES + 63) / 64, 256, 0, stream>>>(
        bufB, Wsp + 0 * HIDDEN * HIDDEN, bsp + 0 * HIDDEN,
        nullptr, nullptr, nullptr, nullptr, dinv, bufA);

    k_agg<HIDDEN><<<(N_NODES + 3) / 4, 256, 0, stream>>>(bufA, col, rowp, dinv, bufB);
    k_gemm<HIDDEN, 1><<<(N_NODES + 63) / 64, 256, 0, stream>>>(
        bufB, Wsp + 1 * HIDDEN * HIDDEN, bsp + 1 * HIDDEN,
        nullptr, nullptr, nullptr, nullptr, dinv, bufA);

    // layer 4: h4 = relu(a@W+b) (unscaled, used for pooling)
    k_agg<HIDDEN><<<(N_NODES + 3) / 4, 256, 0, stream>>>(bufA, col, rowp, dinv, bufB);
    k_gemm<HIDDEN, 2><<<(N_NODES + 63) / 64, 256, 0, stream>>>(
        bufB, Wsp + 2 * HIDDEN * HIDDEN, bsp + 2 * HIDDEN,
        nullptr, nullptr, nullptr, nullptr, dinv, bufA);

    k_head<<<NUM_GRAPHS, 256, 0, stream>>>(bufA, batch, gcnt, W2, b2, out);
}

// Round 2
// 1263.484 us; speedup vs baseline: 2.0077x; 2.0077x over previous
//
#include <hip/hip_runtime.h>
#include <math.h>

#define N_NODES 50000
#define N_EDGES 800000
#define IN_FEAT 128
#define HIDDEN 256
#define NUM_GRAPHS 128
#define NUM_CLASSES 10
#define BN_EPS 1e-5f

#define POOL_SLICES 4    // 4 x 64-feature slices
#define POOL_CHUNKS 64   // node chunks

// ---------------- CSR build ----------------
__global__ void k_count(const int* __restrict__ dst, int* __restrict__ cnt) {
    int e = blockIdx.x * 256 + threadIdx.x;
    if (e < N_EDGES) atomicAdd(&cnt[dst[e]], 1);
}

__global__ void k_count_batch(const int* __restrict__ batch, int* __restrict__ gcnt) {
    int v = blockIdx.x * 256 + threadIdx.x;
    if (v < N_NODES) atomicAdd(&gcnt[batch[v]], 1);
}

// single-block exclusive scan over per-node edge counts; also emits dinv
__global__ void k_scan(const int* __restrict__ cnt, int* __restrict__ row_ptr,
                       int* __restrict__ cursor, float* __restrict__ dinv) {
    __shared__ int part[512];
    int tid = threadIdx.x;                 // 512 threads
    const int CH = (N_NODES + 511) / 512;  // 98
    int lo = tid * CH, hi = min(lo + CH, N_NODES);
    int s = 0;
    for (int i = lo; i < hi; ++i) s += cnt[i];
    part[tid] = s;
    __syncthreads();
    if (tid == 0) {
        int run = 0;
        for (int i = 0; i < 512; ++i) { int t = part[i]; part[i] = run; run += t; }
        row_ptr[N_NODES] = run;
    }
    __syncthreads();
    int run = part[tid];
    for (int i = lo; i < hi; ++i) {
        row_ptr[i] = run;
        cursor[i]  = run;
        int c = cnt[i];
        run += c;
        dinv[i] = rsqrtf(1.0f + (float)c);   // self-loop included in degree
    }
}

__global__ void k_fill(const int* __restrict__ src, const int* __restrict__ dst,
                       int* __restrict__ cursor, int* __restrict__ col) {
    int e = blockIdx.x * 256 + threadIdx.x;
    if (e < N_EDGES) {
        int slot = atomicAdd(&cursor[dst[e]], 1);
        col[slot] = src[e];
    }
}

// ---------------- prescale: p0 = x * dinv[row] ----------------
__global__ void k_prescale(const float* __restrict__ x, const float* __restrict__ dinv,
                           float* __restrict__ p0) {
    int i = blockIdx.x * 256 + threadIdx.x;      // over N*IN_FEAT/4 float4s
    if (i < N_NODES * IN_FEAT / 4) {
        float4 v = ((const float4*)x)[i];
        float d = dinv[i / (IN_FEAT / 4)];
        v.x *= d; v.y *= d; v.z *= d; v.w *= d;
        ((float4*)p0)[i] = v;
    }
}

// ---------------- aggregation: out[v] = dinv[v] * (p[v] + sum p[col]) ----------------
// wave per node, lane handles one float4 of the feature row
template <int F>
__global__ __launch_bounds__(256) void k_agg(const float* __restrict__ p,
                                             const int* __restrict__ col,
                                             const int* __restrict__ row_ptr,
                                             const float* __restrict__ dinv,
                                             float* __restrict__ out) {
    int wave = threadIdx.x >> 6;
    int lane = threadIdx.x & 63;
    int v = blockIdx.x * 4 + wave;
    if (v >= N_NODES) return;
    const int LPF = F / 4;              // float4 slots per row (32 or 64)
    if (lane >= LPF) return;
    float4 acc = ((const float4*)(p + (size_t)v * F))[lane];
    int rp0 = row_ptr[v], rp1 = row_ptr[v + 1];
    for (int i = rp0; i < rp1; ++i) {
        int s = col[i];
        float4 q = ((const float4*)(p + (size_t)s * F))[lane];
        acc.x += q.x; acc.y += q.y; acc.z += q.z; acc.w += q.w;
    }
    float d = dinv[v];
    acc.x *= d; acc.y *= d; acc.z *= d; acc.w *= d;
    ((float4*)(out + (size_t)v * F))[lane] = acc;
}

// ---------------- GEMM: out = epi(A @ W + bias) ----------------
// EPI: 0 = BN+relu then *dinv ; 1 = relu then *dinv ; 2 = relu (plain)
template <int KDIM, int EPI>
__global__ __launch_bounds__(256) void k_gemm(const float* __restrict__ A,
                                              const float* __restrict__ W,
                                              const float* __restrict__ bias,
                                              const float* __restrict__ gamma,
                                              const float* __restrict__ beta,
                                              const float* __restrict__ mean,
                                              const float* __restrict__ var,
                                              const float* __restrict__ dinv,
                                              float* __restrict__ out) {
    __shared__ float As[16][65];
    __shared__ float Bs[16][256];
    int t = threadIdx.x;
    int v0 = blockIdx.x * 64;
    int cg = t & 63;     // cols cg*4 .. cg*4+3
    int rg = t >> 6;     // rows rg*16 .. rg*16+15
    float acc[16][4];
#pragma unroll
    for (int r = 0; r < 16; ++r)
#pragma unroll
        for (int c = 0; c < 4; ++c) acc[r][c] = 0.f;

    int arow = t >> 2;          // 0..63
    int akk  = (t & 3) * 4;     // 0,4,8,12
    for (int k0 = 0; k0 < KDIM; k0 += 16) {
        {
            int grow = v0 + arow;
            float4 av = make_float4(0.f, 0.f, 0.f, 0.f);
            if (grow < N_NODES) av = *(const float4*)(A + (size_t)grow * KDIM + k0 + akk);
            As[akk + 0][arow] = av.x; As[akk + 1][arow] = av.y;
            As[akk + 2][arow] = av.z; As[akk + 3][arow] = av.w;
        }
#pragma unroll
        for (int kk = 0; kk < 16; ++kk) Bs[kk][t] = W[(size_t)(k0 + kk) * HIDDEN + t];
        __syncthreads();
#pragma unroll
        for (int kk = 0; kk < 16; ++kk) {
            float4 b = *(const float4*)&Bs[kk][cg * 4];
#pragma unroll
            for (int r = 0; r < 16; ++r) {
                float a = As[kk][rg * 16 + r];
                acc[r][0] += a * b.x; acc[r][1] += a * b.y;
                acc[r][2] += a * b.z; acc[r][3] += a * b.w;
            }
        }
        __syncthreads();
    }
    int c0 = cg * 4;
    float bi[4], sc[4], sh[4];
#pragma unroll
    for (int j = 0; j < 4; ++j) {
        bi[j] = bias[c0 + j];
        if constexpr (EPI == 0) {
            float s = gamma[c0 + j] * rsqrtf(var[c0 + j] + BN_EPS);
            sc[j] = s; sh[j] = beta[c0 + j] - mean[c0 + j] * s;
        }
    }
#pragma unroll
    for (int r = 0; r < 16; ++r) {
        int grow = v0 + rg * 16 + r;
        if (grow < N_NODES) {
            float d = (EPI == 2) ? 1.f : dinv[grow];
            float o[4];
#pragma unroll
            for (int j = 0; j < 4; ++j) {
                float y = acc[r][j] + bi[j];
                if constexpr (EPI == 0) y = y * sc[j] + sh[j];
                y = fmaxf(y, 0.f);
                o[j] = y * d;
            }
            *(float4*)(out + (size_t)grow * HIDDEN + c0) = make_float4(o[0], o[1], o[2], o[3]);
        }
    }
}

// ---------------- pooling: sums[g][c] += h[v][c] for batch[v]==g ----------------
// grid = POOL_CHUNKS * POOL_SLICES blocks; each block: 64-feat slice, node chunk.
// LDS bins per graph, then one global atomicAdd pass.
__global__ __launch_bounds__(256) void k_pool(const float* __restrict__ h,
                                              const int* __restrict__ batch,
                                              float* __restrict__ sums) {
    __shared__ float acc[NUM_GRAPHS][64];
    int slice = blockIdx.x % POOL_SLICES;
    int chunk = blockIdx.x / POOL_SLICES;
    int t = threadIdx.x;
    for (int i = t; i < NUM_GRAPHS * 64; i += 256) ((float*)acc)[i] = 0.f;
    __syncthreads();
    int lane = t & 63;
    int wv = t >> 6;
    const int per_chunk = (N_NODES + POOL_CHUNKS - 1) / POOL_CHUNKS;
    int v0 = chunk * per_chunk;
    int v1 = min(v0 + per_chunk, N_NODES);
    int c = slice * 64 + lane;
    for (int v = v0 + wv; v < v1; v += 4) {
        int g = batch[v];
        float val = h[(size_t)v * HIDDEN + c];
        atomicAdd(&acc[g][lane], val);
    }
    __syncthreads();
    for (int i = t; i < NUM_GRAPHS * 64; i += 256) {
        float val = ((float*)acc)[i];
        if (val != 0.f) atomicAdd(&sums[(size_t)(i >> 6) * HIDDEN + slice * 64 + (i & 63)], val);
    }
}

// ---------------- logits + log_softmax per graph ----------------
__global__ __launch_bounds__(256) void k_logits(const float* __restrict__ sums,
                                                const int* __restrict__ gcnt,
                                                const float* __restrict__ W2,
                                                const float* __restrict__ b2,
                                                float* __restrict__ outp) {
    __shared__ float pooled[HIDDEN];
    int g = blockIdx.x;
    int t = threadIdx.x;
    float inv = 1.0f / fmaxf((float)gcnt[g], 1.0f);
    pooled[t] = sums[(size_t)g * HIDDEN + t] * inv;
    __syncthreads();
    if (t < 64) {
        float lg = -INFINITY;
        if (t < NUM_CLASSES) {
            lg = b2[t];
            for (int k = 0; k < HIDDEN; ++k) lg += pooled[k] * W2[k * NUM_CLASSES + t];
        }
        float m = lg;
        for (int off = 1; off < 16; off <<= 1) m = fmaxf(m, __shfl_xor(m, off));
        float e = (t < 16) ? expf(lg - m) : 0.f;
        float ssum = e;
        for (int off = 1; off < 16; off <<= 1) ssum += __shfl_xor(ssum, off);
        if (t < NUM_CLASSES) outp[g * NUM_CLASSES + t] = lg - m - logf(ssum);
    }
}

extern "C" void kernel_launch(void* const* d_in, const int* in_sizes, int n_in,
                              void* d_out, int out_size, void* d_ws, size_t ws_size,
                              hipStream_t stream) {
    const float* x     = (const float*)d_in[0];
    const int*   ei    = (const int*)d_in[1];
    const int*   batch = (const int*)d_in[2];
    const float* W1    = (const float*)d_in[3];
    const float* b1    = (const float*)d_in[4];
    const float* gamma = (const float*)d_in[5];
    const float* beta  = (const float*)d_in[6];
    const float* rmean = (const float*)d_in[7];
    const float* rvar  = (const float*)d_in[8];
    const float* Wsp   = (const float*)d_in[9];
    const float* bsp   = (const float*)d_in[10];
    const float* W2    = (const float*)d_in[11];
    const float* b2    = (const float*)d_in[12];
    float* out = (float*)d_out;

    char* w = (char*)d_ws;
    size_t off = 0;
    auto alloc = [&](size_t bytes) -> void* {
        void* p = w + off;
        off = (off + bytes + 255) & ~(size_t)255;
        return p;
    };
    int*   cnt    = (int*)alloc((size_t)N_NODES * 4);
    int*   gcnt   = (int*)alloc((size_t)NUM_GRAPHS * 4);
    int*   rowp   = (int*)alloc((size_t)(N_NODES + 1) * 4);
    int*   cursor = (int*)alloc((size_t)N_NODES * 4);
    int*   col    = (int*)alloc((size_t)N_EDGES * 4);
    float* dinv   = (float*)alloc((size_t)N_NODES * 4);
    float* sums   = (float*)alloc((size_t)NUM_GRAPHS * HIDDEN * 4);
    float* bufA   = (float*)alloc((size_t)N_NODES * HIDDEN * 4);
    float* bufB   = (float*)alloc((size_t)N_NODES * HIDDEN * 4);

    hipMemsetAsync(cnt, 0, (size_t)N_NODES * 4, stream);
    hipMemsetAsync(gcnt, 0, (size_t)NUM_GRAPHS * 4, stream);
    hipMemsetAsync(sums, 0, (size_t)NUM_GRAPHS * HIDDEN * 4, stream);

    const int* srcp = ei;
    const int* dstp = ei + N_EDGES;

    k_count<<<(N_EDGES + 255) / 256, 256, 0, stream>>>(dstp, cnt);
    k_count_batch<<<(N_NODES + 255) / 256, 256, 0, stream>>>(batch, gcnt);
    k_scan<<<1, 512, 0, stream>>>(cnt, rowp, cursor, dinv);
    k_fill<<<(N_EDGES + 255) / 256, 256, 0, stream>>>(srcp, dstp, cursor, col);

    // layer 1: p0 = x*dinv ; a0 = agg(p0) ; bufA = dinv*relu(bn(a0@W1+b1))
    k_prescale<<<(N_NODES * IN_FEAT / 4 + 255) / 256, 256, 0, stream>>>(x, dinv, bufA);
    k_agg<IN_FEAT><<<(N_NODES + 3) / 4, 256, 0, stream>>>(bufA, col, rowp, dinv, bufB);
    k_gemm<IN_FEAT, 0><<<(N_NODES + 63) / 64, 256, 0, stream>>>(
        bufB, W1, b1, gamma, beta, rmean, rvar, dinv, bufA);

    // layers 2..3: p = dinv*relu(a@W+b)
    k_agg<HIDDEN><<<(N_NODES + 3) / 4, 256, 0, stream>>>(bufA, col, rowp, dinv, bufB);
    k_gemm<HIDDEN, 1><<<(N_NODES + 63) / 64, 256, 0, stream>>>(
        bufB, Wsp + 0 * HIDDEN * HIDDEN, bsp + 0 * HIDDEN,
        nullptr, nullptr, nullptr, nullptr, dinv, bufA);

    k_agg<HIDDEN><<<(N_NODES + 3) / 4, 256, 0, stream>>>(bufA, col, rowp, dinv, bufB);
    k_gemm<HIDDEN, 1><<<(N_NODES + 63) / 64, 256, 0, stream>>>(
        bufB, Wsp + 1 * HIDDEN * HIDDEN, bsp + 1 * HIDDEN,
        nullptr, nullptr, nullptr, nullptr, dinv, bufA);

    // layer 4: h4 = relu(a@W+b) (unscaled, used for pooling)
    k_agg<HIDDEN><<<(N_NODES + 3) / 4, 256, 0, stream>>>(bufA, col, rowp, dinv, bufB);
    k_gemm<HIDDEN, 2><<<(N_NODES + 63) / 64, 256, 0, stream>>>(
        bufB, Wsp + 2 * HIDDEN * HIDDEN, bsp + 2 * HIDDEN,
        nullptr, nullptr, nullptr, nullptr, dinv, bufA);

    k_pool<<<POOL_CHUNKS * POOL_SLICES, 256, 0, stream>>>(bufA, batch, sums);
    k_logits<<<NUM_GRAPHS, 256, 0, stream>>>(sums, gcnt, W2, b2, out);
}

// Round 3
// 1111.844 us; speedup vs baseline: 2.2815x; 1.1364x over previous
//
#include <hip/hip_runtime.h>
#include <math.h>

#define N_NODES 50000
#define N_EDGES 800000
#define IN_FEAT 128
#define HIDDEN 256
#define NUM_GRAPHS 128
#define NUM_CLASSES 10
#define BN_EPS 1e-5f

#define POOL_SLICES 4    // 4 x 64-feature slices
#define POOL_CHUNKS 64   // node chunks

#define NCHUNK ((N_NODES + 255) / 256)   // 196 scan chunks

// ---------------- CSR build ----------------
__global__ void k_count(const int* __restrict__ dst, int* __restrict__ cnt) {
    int e = blockIdx.x * 256 + threadIdx.x;
    if (e < N_EDGES) atomicAdd(&cnt[dst[e]], 1);
}

__global__ void k_count_batch(const int* __restrict__ batch, int* __restrict__ gcnt) {
    int v = blockIdx.x * 256 + threadIdx.x;
    if (v < N_NODES) atomicAdd(&gcnt[batch[v]], 1);
}

// ---- hierarchical scan: chunk sums -> scan chunks -> apply ----
__global__ __launch_bounds__(256) void k_chunksum(const int* __restrict__ cnt,
                                                  int* __restrict__ csum) {
    int i = blockIdx.x * 256 + threadIdx.x;
    int v = (i < N_NODES) ? cnt[i] : 0;
#pragma unroll
    for (int off = 32; off; off >>= 1) v += __shfl_down(v, off, 64);
    __shared__ int ws[4];
    if ((threadIdx.x & 63) == 0) ws[threadIdx.x >> 6] = v;
    __syncthreads();
    if (threadIdx.x == 0) csum[blockIdx.x] = ws[0] + ws[1] + ws[2] + ws[3];
}

__global__ __launch_bounds__(256) void k_scanchunks(const int* __restrict__ csum,
                                                    int* __restrict__ choff) {
    __shared__ int s[256];
    int t = threadIdx.x;
    int v = (t < NCHUNK) ? csum[t] : 0;
    s[t] = v;
    __syncthreads();
#pragma unroll
    for (int off = 1; off < 256; off <<= 1) {
        int add = (t >= off) ? s[t - off] : 0;
        __syncthreads();
        s[t] += add;
        __syncthreads();
    }
    if (t < NCHUNK) choff[t] = s[t] - v;   // exclusive
}

__global__ __launch_bounds__(256) void k_apply(const int* __restrict__ cnt,
                                               const int* __restrict__ choff,
                                               int* __restrict__ rowp,
                                               int* __restrict__ cursor,
                                               float* __restrict__ dinv) {
    __shared__ int s[256];
    int t = threadIdx.x;
    int i = blockIdx.x * 256 + t;
    int c = (i < N_NODES) ? cnt[i] : 0;
    s[t] = c;
    __syncthreads();
#pragma unroll
    for (int off = 1; off < 256; off <<= 1) {
        int add = (t >= off) ? s[t - off] : 0;
        __syncthreads();
        s[t] += add;
        __syncthreads();
    }
    int incl = s[t];
    int base = choff[blockIdx.x];
    if (i < N_NODES) {
        int ex = base + incl - c;
        rowp[i] = ex;
        cursor[i] = ex;
        dinv[i] = rsqrtf(1.0f + (float)c);   // self-loop included in degree
        if (i == N_NODES - 1) rowp[N_NODES] = base + incl;
    }
}

__global__ void k_fill(const int* __restrict__ src, const int* __restrict__ dst,
                       int* __restrict__ cursor, int* __restrict__ col) {
    int e = blockIdx.x * 256 + threadIdx.x;
    if (e < N_EDGES) {
        int slot = atomicAdd(&cursor[dst[e]], 1);
        col[slot] = src[e];
    }
}

// ---------------- prescale: p0 = x * dinv[row] ----------------
__global__ void k_prescale(const float* __restrict__ x, const float* __restrict__ dinv,
                           float* __restrict__ p0) {
    int i = blockIdx.x * 256 + threadIdx.x;      // over N*IN_FEAT/4 float4s
    if (i < N_NODES * IN_FEAT / 4) {
        float4 v = ((const float4*)x)[i];
        float d = dinv[i / (IN_FEAT / 4)];
        v.x *= d; v.y *= d; v.z *= d; v.w *= d;
        ((float4*)p0)[i] = v;
    }
}

// ---------------- aggregation: out[v] = dinv[v] * (p[v] + sum p[col]) ----------------
// wave per node. F=256: lane = one float4 (64*16B = 1KB row).
// F=128: lane = one float2 (64*8B = 512B row) so all 64 lanes stay active.
template <int F>
__global__ __launch_bounds__(256) void k_agg(const float* __restrict__ p,
                                             const int* __restrict__ col,
                                             const int* __restrict__ row_ptr,
                                             const float* __restrict__ dinv,
                                             float* __restrict__ out) {
    int wave = threadIdx.x >> 6;
    int lane = threadIdx.x & 63;
    int v = blockIdx.x * 4 + wave;
    if (v >= N_NODES) return;
    int rp0 = row_ptr[v], rp1 = row_ptr[v + 1];
    float d = dinv[v];
    if constexpr (F == 128) {
        float2 acc = ((const float2*)(p + (size_t)v * F))[lane];
        for (int i = rp0; i < rp1; ++i) {
            int s = col[i];
            float2 q = ((const float2*)(p + (size_t)s * F))[lane];
            acc.x += q.x; acc.y += q.y;
        }
        acc.x *= d; acc.y *= d;
        ((float2*)(out + (size_t)v * F))[lane] = acc;
    } else {
        float4 acc = ((const float4*)(p + (size_t)v * F))[lane];
        for (int i = rp0; i < rp1; ++i) {
            int s = col[i];
            float4 q = ((const float4*)(p + (size_t)s * F))[lane];
            acc.x += q.x; acc.y += q.y; acc.z += q.z; acc.w += q.w;
        }
        acc.x *= d; acc.y *= d; acc.z *= d; acc.w *= d;
        ((float4*)(out + (size_t)v * F))[lane] = acc;
    }
}

// ---------------- GEMM: out = epi(A @ W + bias) ----------------
// EPI: 0 = BN+relu then *dinv ; 1 = relu then *dinv ; 2 = relu (plain)
template <int KDIM, int EPI>
__global__ __launch_bounds__(256) void k_gemm(const float* __restrict__ A,
                                              const float* __restrict__ W,
                                              const float* __restrict__ bias,
                                              const float* __restrict__ gamma,
                                              const float* __restrict__ beta,
                                              const float* __restrict__ mean,
                                              const float* __restrict__ var,
                                              const float* __restrict__ dinv,
                                              float* __restrict__ out) {
    __shared__ float As[16][65];
    __shared__ float Bs[16][256];
    int t = threadIdx.x;
    int v0 = blockIdx.x * 64;
    int cg = t & 63;     // cols cg*4 .. cg*4+3
    int rg = t >> 6;     // rows rg*16 .. rg*16+15
    float acc[16][4];
#pragma unroll
    for (int r = 0; r < 16; ++r)
#pragma unroll
        for (int c = 0; c < 4; ++c) acc[r][c] = 0.f;

    int arow = t >> 2;          // 0..63
    int akk  = (t & 3) * 4;     // 0,4,8,12
    for (int k0 = 0; k0 < KDIM; k0 += 16) {
        {
            int grow = v0 + arow;
            float4 av = make_float4(0.f, 0.f, 0.f, 0.f);
            if (grow < N_NODES) av = *(const float4*)(A + (size_t)grow * KDIM + k0 + akk);
            As[akk + 0][arow] = av.x; As[akk + 1][arow] = av.y;
            As[akk + 2][arow] = av.z; As[akk + 3][arow] = av.w;
        }
#pragma unroll
        for (int kk = 0; kk < 16; ++kk) Bs[kk][t] = W[(size_t)(k0 + kk) * HIDDEN + t];
        __syncthreads();
#pragma unroll
        for (int kk = 0; kk < 16; ++kk) {
            float4 b = *(const float4*)&Bs[kk][cg * 4];
#pragma unroll
            for (int r = 0; r < 16; ++r) {
                float a = As[kk][rg * 16 + r];
                acc[r][0] += a * b.x; acc[r][1] += a * b.y;
                acc[r][2] += a * b.z; acc[r][3] += a * b.w;
            }
        }
        __syncthreads();
    }
    int c0 = cg * 4;
    float bi[4], sc[4], sh[4];
#pragma unroll
    for (int j = 0; j < 4; ++j) {
        bi[j] = bias[c0 + j];
        if constexpr (EPI == 0) {
            float s = gamma[c0 + j] * rsqrtf(var[c0 + j] + BN_EPS);
            sc[j] = s; sh[j] = beta[c0 + j] - mean[c0 + j] * s;
        }
    }
#pragma unroll
    for (int r = 0; r < 16; ++r) {
        int grow = v0 + rg * 16 + r;
        if (grow < N_NODES) {
            float d = (EPI == 2) ? 1.f : dinv[grow];
            float o[4];
#pragma unroll
            for (int j = 0; j < 4; ++j) {
                float y = acc[r][j] + bi[j];
                if constexpr (EPI == 0) y = y * sc[j] + sh[j];
                y = fmaxf(y, 0.f);
                o[j] = y * d;
            }
            *(float4*)(out + (size_t)grow * HIDDEN + c0) = make_float4(o[0], o[1], o[2], o[3]);
        }
    }
}

// ---------------- pooling: sums[g][c] += h[v][c] for batch[v]==g ----------------
__global__ __launch_bounds__(256) void k_pool(const float* __restrict__ h,
                                              const int* __restrict__ batch,
                                              float* __restrict__ sums) {
    __shared__ float acc[NUM_GRAPHS][64];
    int slice = blockIdx.x % POOL_SLICES;
    int chunk = blockIdx.x / POOL_SLICES;
    int t = threadIdx.x;
    for (int i = t; i < NUM_GRAPHS * 64; i += 256) ((float*)acc)[i] = 0.f;
    __syncthreads();
    int lane = t & 63;
    int wv = t >> 6;
    const int per_chunk = (N_NODES + POOL_CHUNKS - 1) / POOL_CHUNKS;
    int v0 = chunk * per_chunk;
    int v1 = min(v0 + per_chunk, N_NODES);
    int c = slice * 64 + lane;
    for (int v = v0 + wv; v < v1; v += 4) {
        int g = batch[v];
        float val = h[(size_t)v * HIDDEN + c];
        atomicAdd(&acc[g][lane], val);
    }
    __syncthreads();
    for (int i = t; i < NUM_GRAPHS * 64; i += 256) {
        float val = ((float*)acc)[i];
        if (val != 0.f) atomicAdd(&sums[(size_t)(i >> 6) * HIDDEN + slice * 64 + (i & 63)], val);
    }
}

// ---------------- logits + log_softmax per graph ----------------
__global__ __launch_bounds__(256) void k_logits(const float* __restrict__ sums,
                                                const int* __restrict__ gcnt,
                                                const float* __restrict__ W2,
                                                const float* __restrict__ b2,
                                                float* __restrict__ outp) {
    __shared__ float pooled[HIDDEN];
    int g = blockIdx.x;
    int t = threadIdx.x;
    float inv = 1.0f / fmaxf((float)gcnt[g], 1.0f);
    pooled[t] = sums[(size_t)g * HIDDEN + t] * inv;
    __syncthreads();
    if (t < 64) {
        float lg = -INFINITY;
        if (t < NUM_CLASSES) {
            lg = b2[t];
            for (int k = 0; k < HIDDEN; ++k) lg += pooled[k] * W2[k * NUM_CLASSES + t];
        }
        float m = lg;
        for (int off = 1; off < 16; off <<= 1) m = fmaxf(m, __shfl_xor(m, off));
        float e = (t < 16) ? expf(lg - m) : 0.f;
        float ssum = e;
        for (int off = 1; off < 16; off <<= 1) ssum += __shfl_xor(ssum, off);
        if (t < NUM_CLASSES) outp[g * NUM_CLASSES + t] = lg - m - logf(ssum);
    }
}

extern "C" void kernel_launch(void* const* d_in, const int* in_sizes, int n_in,
                              void* d_out, int out_size, void* d_ws, size_t ws_size,
                              hipStream_t stream) {
    const float* x     = (const float*)d_in[0];
    const int*   ei    = (const int*)d_in[1];
    const int*   batch = (const int*)d_in[2];
    const float* W1    = (const float*)d_in[3];
    const float* b1    = (const float*)d_in[4];
    const float* gamma = (const float*)d_in[5];
    const float* beta  = (const float*)d_in[6];
    const float* rmean = (const float*)d_in[7];
    const float* rvar  = (const float*)d_in[8];
    const float* Wsp   = (const float*)d_in[9];
    const float* bsp   = (const float*)d_in[10];
    const float* W2    = (const float*)d_in[11];
    const float* b2    = (const float*)d_in[12];
    float* out = (float*)d_out;

    char* w = (char*)d_ws;
    size_t off = 0;
    auto alloc = [&](size_t bytes) -> void* {
        void* p = w + off;
        off = (off + bytes + 255) & ~(size_t)255;
        return p;
    };
    int*   cnt    = (int*)alloc((size_t)N_NODES * 4);
    int*   gcnt   = (int*)alloc((size_t)NUM_GRAPHS * 4);
    int*   rowp   = (int*)alloc((size_t)(N_NODES + 1) * 4);
    int*   cursor = (int*)alloc((size_t)N_NODES * 4);
    int*   col    = (int*)alloc((size_t)N_EDGES * 4);
    float* dinv   = (float*)alloc((size_t)N_NODES * 4);
    int*   csum   = (int*)alloc((size_t)NCHUNK * 4);
    int*   choff  = (int*)alloc((size_t)NCHUNK * 4);
    float* sums   = (float*)alloc((size_t)NUM_GRAPHS * HIDDEN * 4);
    float* bufA   = (float*)alloc((size_t)N_NODES * HIDDEN * 4);
    float* bufB   = (float*)alloc((size_t)N_NODES * HIDDEN * 4);

    hipMemsetAsync(cnt, 0, (size_t)N_NODES * 4, stream);
    hipMemsetAsync(gcnt, 0, (size_t)NUM_GRAPHS * 4, stream);
    hipMemsetAsync(sums, 0, (size_t)NUM_GRAPHS * HIDDEN * 4, stream);

    const int* srcp = ei;
    const int* dstp = ei + N_EDGES;

    k_count<<<(N_EDGES + 255) / 256, 256, 0, stream>>>(dstp, cnt);
    k_count_batch<<<(N_NODES + 255) / 256, 256, 0, stream>>>(batch, gcnt);
    k_chunksum<<<NCHUNK, 256, 0, stream>>>(cnt, csum);
    k_scanchunks<<<1, 256, 0, stream>>>(csum, choff);
    k_apply<<<NCHUNK, 256, 0, stream>>>(cnt, choff, rowp, cursor, dinv);
    k_fill<<<(N_EDGES + 255) / 256, 256, 0, stream>>>(srcp, dstp, cursor, col);

    // layer 1: p0 = x*dinv ; a0 = agg(p0) ; bufA = dinv*relu(bn(a0@W1+b1))
    k_prescale<<<(N_NODES * IN_FEAT / 4 + 255) / 256, 256, 0, stream>>>(x, dinv, bufA);
    k_agg<IN_FEAT><<<(N_NODES + 3) / 4, 256, 0, stream>>>(bufA, col, rowp, dinv, bufB);
    k_gemm<IN_FEAT, 0><<<(N_NODES + 63) / 64, 256, 0, stream>>>(
        bufB, W1, b1, gamma, beta, rmean, rvar, dinv, bufA);

    // layers 2..3: p = dinv*relu(a@W+b)
    k_agg<HIDDEN><<<(N_NODES + 3) / 4, 256, 0, stream>>>(bufA, col, rowp, dinv, bufB);
    k_gemm<HIDDEN, 1><<<(N_NODES + 63) / 64, 256, 0, stream>>>(
        bufB, Wsp + 0 * HIDDEN * HIDDEN, bsp + 0 * HIDDEN,
        nullptr, nullptr, nullptr, nullptr, dinv, bufA);

    k_agg<HIDDEN><<<(N_NODES + 3) / 4, 256, 0, stream>>>(bufA, col, rowp, dinv, bufB);
    k_gemm<HIDDEN, 1><<<(N_NODES + 63) / 64, 256, 0, stream>>>(
        bufB, Wsp + 1 * HIDDEN * HIDDEN, bsp + 1 * HIDDEN,
        nullptr, nullptr, nullptr, nullptr, dinv, bufA);

    // layer 4: h4 = relu(a@W+b) (unscaled, used for pooling)
    k_agg<HIDDEN><<<(N_NODES + 3) / 4, 256, 0, stream>>>(bufA, col, rowp, dinv, bufB);
    k_gemm<HIDDEN, 2><<<(N_NODES + 63) / 64, 256, 0, stream>>>(
        bufB, Wsp + 2 * HIDDEN * HIDDEN, bsp + 2 * HIDDEN,
        nullptr, nullptr, nullptr, nullptr, dinv, bufA);

    k_pool<<<POOL_CHUNKS * POOL_SLICES, 256, 0, stream>>>(bufA, batch, sums);
    k_logits<<<NUM_GRAPHS, 256, 0, stream>>>(sums, gcnt, W2, b2, out);
}

// Round 4
// 759.700 us; speedup vs baseline: 3.3391x; 1.4635x over previous
//
#include <hip/hip_runtime.h>
#include <math.h>

#define N_NODES 50000
#define N_EDGES 800000
#define IN_FEAT 128
#define HIDDEN 256
#define NUM_GRAPHS 128
#define NUM_CLASSES 10
#define BN_EPS 1e-5f

#define POOL_SLICES 4
#define POOL_CHUNKS 64
#define NCHUNK ((N_NODES + 255) / 256)   // 196 scan chunks

typedef __attribute__((ext_vector_type(8))) short bf16x8;
typedef __attribute__((ext_vector_type(4))) float f32x4;

__device__ __forceinline__ ushort f2bf(float f) {
    union { float f; uint u; } c; c.f = f;
    uint u = c.u;
    return (ushort)((u + 0x7FFFu + ((u >> 16) & 1u)) >> 16);   // RNE
}
__device__ __forceinline__ float bf2f(ushort h) {
    union { uint u; float f; } c; c.u = ((uint)h) << 16;
    return c.f;
}

// ---------------- CSR build ----------------
__global__ void k_count(const int* __restrict__ dst, int* __restrict__ cnt) {
    int e = blockIdx.x * 256 + threadIdx.x;
    if (e < N_EDGES) atomicAdd(&cnt[dst[e]], 1);
}

__global__ void k_count_batch(const int* __restrict__ batch, int* __restrict__ gcnt) {
    int v = blockIdx.x * 256 + threadIdx.x;
    if (v < N_NODES) atomicAdd(&gcnt[batch[v]], 1);
}

__global__ __launch_bounds__(256) void k_chunksum(const int* __restrict__ cnt,
                                                  int* __restrict__ csum) {
    int i = blockIdx.x * 256 + threadIdx.x;
    int v = (i < N_NODES) ? cnt[i] : 0;
#pragma unroll
    for (int off = 32; off; off >>= 1) v += __shfl_down(v, off, 64);
    __shared__ int ws[4];
    if ((threadIdx.x & 63) == 0) ws[threadIdx.x >> 6] = v;
    __syncthreads();
    if (threadIdx.x == 0) csum[blockIdx.x] = ws[0] + ws[1] + ws[2] + ws[3];
}

__global__ __launch_bounds__(256) void k_scanchunks(const int* __restrict__ csum,
                                                    int* __restrict__ choff) {
    __shared__ int s[256];
    int t = threadIdx.x;
    int v = (t < NCHUNK) ? csum[t] : 0;
    s[t] = v;
    __syncthreads();
#pragma unroll
    for (int off = 1; off < 256; off <<= 1) {
        int add = (t >= off) ? s[t - off] : 0;
        __syncthreads();
        s[t] += add;
        __syncthreads();
    }
    if (t < NCHUNK) choff[t] = s[t] - v;   // exclusive
}

__global__ __launch_bounds__(256) void k_apply(const int* __restrict__ cnt,
                                               const int* __restrict__ choff,
                                               int* __restrict__ rowp,
                                               int* __restrict__ cursor,
                                               float* __restrict__ dinv) {
    __shared__ int s[256];
    int t = threadIdx.x;
    int i = blockIdx.x * 256 + t;
    int c = (i < N_NODES) ? cnt[i] : 0;
    s[t] = c;
    __syncthreads();
#pragma unroll
    for (int off = 1; off < 256; off <<= 1) {
        int add = (t >= off) ? s[t - off] : 0;
        __syncthreads();
        s[t] += add;
        __syncthreads();
    }
    int incl = s[t];
    int base = choff[blockIdx.x];
    if (i < N_NODES) {
        int ex = base + incl - c;
        rowp[i] = ex;
        cursor[i] = ex;
        dinv[i] = rsqrtf(1.0f + (float)c);
        if (i == N_NODES - 1) rowp[N_NODES] = base + incl;
    }
}

__global__ void k_fill(const int* __restrict__ src, const int* __restrict__ dst,
                       int* __restrict__ cursor, int* __restrict__ col) {
    int e = blockIdx.x * 256 + threadIdx.x;
    if (e < N_EDGES) {
        int slot = atomicAdd(&cursor[dst[e]], 1);
        col[slot] = src[e];
    }
}

// ---------------- prescale: p0 = bf16(x * dinv[row]) ----------------
__global__ void k_prescale(const float* __restrict__ x, const float* __restrict__ dinv,
                           ushort* __restrict__ p0) {
    int i = blockIdx.x * 256 + threadIdx.x;      // per 4 elems
    if (i < N_NODES * IN_FEAT / 4) {
        float4 v = ((const float4*)x)[i];
        float d = dinv[i / (IN_FEAT / 4)];
        ushort4 o;
        o.x = f2bf(v.x * d); o.y = f2bf(v.y * d);
        o.z = f2bf(v.z * d); o.w = f2bf(v.w * d);
        ((ushort4*)p0)[i] = o;
    }
}

// ---------------- aggregation (bf16 rows, fp32 accum) ----------------
template <int F>
__global__ __launch_bounds__(256) void k_agg(const ushort* __restrict__ p,
                                             const int* __restrict__ col,
                                             const int* __restrict__ row_ptr,
                                             const float* __restrict__ dinv,
                                             ushort* __restrict__ out) {
    int wave = threadIdx.x >> 6;
    int lane = threadIdx.x & 63;
    int v = blockIdx.x * 4 + wave;
    if (v >= N_NODES) return;
    int rp0 = row_ptr[v], rp1 = row_ptr[v + 1];
    float d = dinv[v];
    if constexpr (F == 256) {
        ushort4 me = ((const ushort4*)(p + (size_t)v * F))[lane];
        float a0 = bf2f(me.x), a1 = bf2f(me.y), a2 = bf2f(me.z), a3 = bf2f(me.w);
        for (int i = rp0; i < rp1; ++i) {
            int s = col[i];
            ushort4 q = ((const ushort4*)(p + (size_t)s * F))[lane];
            a0 += bf2f(q.x); a1 += bf2f(q.y); a2 += bf2f(q.z); a3 += bf2f(q.w);
        }
        ushort4 o;
        o.x = f2bf(a0 * d); o.y = f2bf(a1 * d); o.z = f2bf(a2 * d); o.w = f2bf(a3 * d);
        ((ushort4*)(out + (size_t)v * F))[lane] = o;
    } else {
        ushort2 me = ((const ushort2*)(p + (size_t)v * F))[lane];
        float a0 = bf2f(me.x), a1 = bf2f(me.y);
        for (int i = rp0; i < rp1; ++i) {
            int s = col[i];
            ushort2 q = ((const ushort2*)(p + (size_t)s * F))[lane];
            a0 += bf2f(q.x); a1 += bf2f(q.y);
        }
        ushort2 o;
        o.x = f2bf(a0 * d); o.y = f2bf(a1 * d);
        ((ushort2*)(out + (size_t)v * F))[lane] = o;
    }
}

// ---------------- W repack: fp32 [K][256] -> bf16 frag layout [nt][kt][lane][8] ----------------
template <int KDIM>
__global__ void k_repackW(const float* __restrict__ W, ushort* __restrict__ Wp) {
    const int KT = KDIM / 32;
    int tid = blockIdx.x * 256 + threadIdx.x;
    if (tid >= 16 * KT * 64) return;
    int lane = tid & 63;
    int kt = (tid >> 6) % KT;
    int nt = (tid >> 6) / KT;
    int n = nt * 16 + (lane & 15);
    int kb = kt * 32 + (lane >> 4) * 8;
    ushort o[8];
#pragma unroll
    for (int j = 0; j < 8; ++j) o[j] = f2bf(W[(size_t)(kb + j) * HIDDEN + n]);
    ushort4* dst = (ushort4*)(Wp + (size_t)tid * 8);
    dst[0] = make_ushort4(o[0], o[1], o[2], o[3]);
    dst[1] = make_ushort4(o[4], o[5], o[6], o[7]);
}

// ---------------- MFMA GEMM: out = epi(A @ W + bias), bf16 in/out, fp32 acc ----------------
// EPI: 0 = BN+relu then *dinv ; 1 = relu then *dinv ; 2 = relu (plain)
// block = 4 waves; wave = 16 rows x 256 cols; grid = ceil(N/64)
template <int KDIM, int EPI>
__global__ __launch_bounds__(256) void k_mgemm(const ushort* __restrict__ A,
                                               const ushort* __restrict__ Wp,
                                               const float* __restrict__ bias,
                                               const float* __restrict__ gamma,
                                               const float* __restrict__ beta,
                                               const float* __restrict__ mean,
                                               const float* __restrict__ var,
                                               const float* __restrict__ dinv,
                                               ushort* __restrict__ out) {
    const int KT = KDIM / 32;
    int t = threadIdx.x;
    int wv = t >> 6, lane = t & 63;
    int row0 = blockIdx.x * 64 + wv * 16;
    int g = lane >> 4, r16 = lane & 15;
    int arow = row0 + r16;
    if (arow >= N_NODES) arow = N_NODES - 1;   // safe load; store guarded

    f32x4 acc[16];
#pragma unroll
    for (int nt = 0; nt < 16; ++nt) acc[nt] = (f32x4){0.f, 0.f, 0.f, 0.f};

    const ushort* aptr = A + (size_t)arow * KDIM + g * 8;
    for (int kt = 0; kt < KT; ++kt) {
        bf16x8 af = *(const bf16x8*)(aptr + kt * 32);
#pragma unroll
        for (int nt = 0; nt < 16; ++nt) {
            bf16x8 bfv = *(const bf16x8*)(Wp + ((size_t)(nt * KT + kt) * 64 + lane) * 8);
            acc[nt] = __builtin_amdgcn_mfma_f32_16x16x32_bf16(af, bfv, acc[nt], 0, 0, 0);
        }
    }

    // epilogue: lane covers rows row0+g*4+r (r=0..3), col nt*16+r16
    int rowb = row0 + g * 4;
    float dv[4];
#pragma unroll
    for (int r = 0; r < 4; ++r) {
        int grow = rowb + r;
        dv[r] = 1.f;
        if (EPI != 2 && grow < N_NODES) dv[r] = dinv[grow];
    }
#pragma unroll
    for (int nt = 0; nt < 16; ++nt) {
        int colc = nt * 16 + r16;
        float bi = bias[colc];
        float sc = 1.f, sh = 0.f;
        if constexpr (EPI == 0) {
            float s = gamma[colc] * rsqrtf(var[colc] + BN_EPS);
            sc = s; sh = beta[colc] - mean[colc] * s;
        }
#pragma unroll
        for (int r = 0; r < 4; ++r) {
            int grow = rowb + r;
            if (grow < N_NODES) {
                float y = acc[nt][r] + bi;
                if constexpr (EPI == 0) y = y * sc + sh;
                y = fmaxf(y, 0.f);
                y *= dv[r];
                out[(size_t)grow * HIDDEN + colc] = f2bf(y);
            }
        }
    }
}

// ---------------- pooling: sums[g][c] += h[v][c] (bf16 h, fp32 sums) ----------------
__global__ __launch_bounds__(256) void k_pool(const ushort* __restrict__ h,
                                              const int* __restrict__ batch,
                                              float* __restrict__ sums) {
    __shared__ float acc[NUM_GRAPHS][64];
    int slice = blockIdx.x % POOL_SLICES;
    int chunk = blockIdx.x / POOL_SLICES;
    int t = threadIdx.x;
    for (int i = t; i < NUM_GRAPHS * 64; i += 256) ((float*)acc)[i] = 0.f;
    __syncthreads();
    int lane = t & 63;
    int wv = t >> 6;
    const int per_chunk = (N_NODES + POOL_CHUNKS - 1) / POOL_CHUNKS;
    int v0 = chunk * per_chunk;
    int v1 = min(v0 + per_chunk, N_NODES);
    int c = slice * 64 + lane;
    for (int v = v0 + wv; v < v1; v += 4) {
        int g = batch[v];
        float val = bf2f(h[(size_t)v * HIDDEN + c]);
        atomicAdd(&acc[g][lane], val);
    }
    __syncthreads();
    for (int i = t; i < NUM_GRAPHS * 64; i += 256) {
        float val = ((float*)acc)[i];
        if (val != 0.f) atomicAdd(&sums[(size_t)(i >> 6) * HIDDEN + slice * 64 + (i & 63)], val);
    }
}

// ---------------- logits + log_softmax per graph ----------------
__global__ __launch_bounds__(256) void k_logits(const float* __restrict__ sums,
                                                const int* __restrict__ gcnt,
                                                const float* __restrict__ W2,
                                                const float* __restrict__ b2,
                                                float* __restrict__ outp) {
    __shared__ float pooled[HIDDEN];
    int g = blockIdx.x;
    int t = threadIdx.x;
    float inv = 1.0f / fmaxf((float)gcnt[g], 1.0f);
    pooled[t] = sums[(size_t)g * HIDDEN + t] * inv;
    __syncthreads();
    if (t < 64) {
        float lg = -INFINITY;
        if (t < NUM_CLASSES) {
            lg = b2[t];
            for (int k = 0; k < HIDDEN; ++k) lg += pooled[k] * W2[k * NUM_CLASSES + t];
        }
        float m = lg;
        for (int off = 1; off < 16; off <<= 1) m = fmaxf(m, __shfl_xor(m, off));
        float e = (t < 16) ? expf(lg - m) : 0.f;
        float ssum = e;
        for (int off = 1; off < 16; off <<= 1) ssum += __shfl_xor(ssum, off);
        if (t < NUM_CLASSES) outp[g * NUM_CLASSES + t] = lg - m - logf(ssum);
    }
}

extern "C" void kernel_launch(void* const* d_in, const int* in_sizes, int n_in,
                              void* d_out, int out_size, void* d_ws, size_t ws_size,
                              hipStream_t stream) {
    const float* x     = (const float*)d_in[0];
    const int*   ei    = (const int*)d_in[1];
    const int*   batch = (const int*)d_in[2];
    const float* W1    = (const float*)d_in[3];
    const float* b1    = (const float*)d_in[4];
    const float* gamma = (const float*)d_in[5];
    const float* beta  = (const float*)d_in[6];
    const float* rmean = (const float*)d_in[7];
    const float* rvar  = (const float*)d_in[8];
    const float* Wsp   = (const float*)d_in[9];
    const float* bsp   = (const float*)d_in[10];
    const float* W2    = (const float*)d_in[11];
    const float* b2    = (const float*)d_in[12];
    float* out = (float*)d_out;

    char* w = (char*)d_ws;
    size_t off = 0;
    auto alloc = [&](size_t bytes) -> void* {
        void* p = w + off;
        off = (off + bytes + 255) & ~(size_t)255;
        return p;
    };
    int*    cnt    = (int*)alloc((size_t)N_NODES * 4);
    int*    gcnt   = (int*)alloc((size_t)NUM_GRAPHS * 4);
    int*    rowp   = (int*)alloc((size_t)(N_NODES + 1) * 4);
    int*    cursor = (int*)alloc((size_t)N_NODES * 4);
    int*    col    = (int*)alloc((size_t)N_EDGES * 4);
    float*  dinv   = (float*)alloc((size_t)N_NODES * 4);
    int*    csum   = (int*)alloc((size_t)NCHUNK * 4);
    int*    choff  = (int*)alloc((size_t)NCHUNK * 4);
    float*  sums   = (float*)alloc((size_t)NUM_GRAPHS * HIDDEN * 4);
    ushort* Wp1    = (ushort*)alloc((size_t)16 * 4 * 64 * 8 * 2);
    ushort* Wp2    = (ushort*)alloc((size_t)16 * 8 * 64 * 8 * 2);
    ushort* Wp3    = (ushort*)alloc((size_t)16 * 8 * 64 * 8 * 2);
    ushort* Wp4    = (ushort*)alloc((size_t)16 * 8 * 64 * 8 * 2);
    ushort* bufA   = (ushort*)alloc((size_t)N_NODES * HIDDEN * 2);
    ushort* bufB   = (ushort*)alloc((size_t)N_NODES * HIDDEN * 2);

    hipMemsetAsync(cnt, 0, (size_t)N_NODES * 4, stream);
    hipMemsetAsync(gcnt, 0, (size_t)NUM_GRAPHS * 4, stream);
    hipMemsetAsync(sums, 0, (size_t)NUM_GRAPHS * HIDDEN * 4, stream);

    const int* srcp = ei;
    const int* dstp = ei + N_EDGES;

    // CSR + degree
    k_count<<<(N_EDGES + 255) / 256, 256, 0, stream>>>(dstp, cnt);
    k_count_batch<<<(N_NODES + 255) / 256, 256, 0, stream>>>(batch, gcnt);
    k_chunksum<<<NCHUNK, 256, 0, stream>>>(cnt, csum);
    k_scanchunks<<<1, 256, 0, stream>>>(csum, choff);
    k_apply<<<NCHUNK, 256, 0, stream>>>(cnt, choff, rowp, cursor, dinv);
    k_fill<<<(N_EDGES + 255) / 256, 256, 0, stream>>>(srcp, dstp, cursor, col);

    // weight repack (fp32 -> bf16 fragment layout)
    k_repackW<IN_FEAT><<<(16 * 4 * 64 + 255) / 256, 256, 0, stream>>>(W1, Wp1);
    k_repackW<HIDDEN><<<(16 * 8 * 64 + 255) / 256, 256, 0, stream>>>(Wsp + 0 * HIDDEN * HIDDEN, Wp2);
    k_repackW<HIDDEN><<<(16 * 8 * 64 + 255) / 256, 256, 0, stream>>>(Wsp + 1 * HIDDEN * HIDDEN, Wp3);
    k_repackW<HIDDEN><<<(16 * 8 * 64 + 255) / 256, 256, 0, stream>>>(Wsp + 2 * HIDDEN * HIDDEN, Wp4);

    const int GG = (N_NODES + 63) / 64;

    // layer 1
    k_prescale<<<(N_NODES * IN_FEAT / 4 + 255) / 256, 256, 0, stream>>>(x, dinv, bufA);
    k_agg<IN_FEAT><<<(N_NODES + 3) / 4, 256, 0, stream>>>(bufA, col, rowp, dinv, bufB);
    k_mgemm<IN_FEAT, 0><<<GG, 256, 0, stream>>>(bufB, Wp1, b1, gamma, beta, rmean, rvar, dinv, bufA);

    // layers 2..3
    k_agg<HIDDEN><<<(N_NODES + 3) / 4, 256, 0, stream>>>(bufA, col, rowp, dinv, bufB);
    k_mgemm<HIDDEN, 1><<<GG, 256, 0, stream>>>(bufB, Wp2, bsp + 0 * HIDDEN,
                                               nullptr, nullptr, nullptr, nullptr, dinv, bufA);

    k_agg<HIDDEN><<<(N_NODES + 3) / 4, 256, 0, stream>>>(bufA, col, rowp, dinv, bufB);
    k_mgemm<HIDDEN, 1><<<GG, 256, 0, stream>>>(bufB, Wp3, bsp + 1 * HIDDEN,
                                               nullptr, nullptr, nullptr, nullptr, dinv, bufA);

    // layer 4 (plain relu, feeds pooling)
    k_agg<HIDDEN><<<(N_NODES + 3) / 4, 256, 0, stream>>>(bufA, col, rowp, dinv, bufB);
    k_mgemm<HIDDEN, 2><<<GG, 256, 0, stream>>>(bufB, Wp4, bsp + 2 * HIDDEN,
                                               nullptr, nullptr, nullptr, nullptr, dinv, bufA);

    k_pool<<<POOL_CHUNKS * POOL_SLICES, 256, 0, stream>>>(bufA, batch, sums);
    k_logits<<<NUM_GRAPHS, 256, 0, stream>>>(sums, gcnt, W2, b2, out);
}

// Round 5
// 630.759 us; speedup vs baseline: 4.0216x; 1.2044x over previous
//
#include <hip/hip_runtime.h>
#include <math.h>

#define N_NODES 50000
#define N_EDGES 800000
#define IN_FEAT 128
#define HIDDEN 256
#define NUM_GRAPHS 128
#define NUM_CLASSES 10
#define BN_EPS 1e-5f

#define POOL_SLICES 4
#define POOL_CHUNKS 64
#define NCHUNK ((N_NODES + 255) / 256)   // 196 scan chunks

typedef __attribute__((ext_vector_type(8))) short bf16x8;
typedef __attribute__((ext_vector_type(4))) float f32x4;

__device__ __forceinline__ ushort f2bf(float f) {
    union { float f; uint u; } c; c.f = f;
    uint u = c.u;
    return (ushort)((u + 0x7FFFu + ((u >> 16) & 1u)) >> 16);   // RNE
}
__device__ __forceinline__ float bf2f(ushort h) {
    union { uint u; float f; } c; c.u = ((uint)h) << 16;
    return c.f;
}

// ---------------- CSR build ----------------
__global__ void k_count(const int* __restrict__ dst, int* __restrict__ cnt) {
    int e = blockIdx.x * 256 + threadIdx.x;
    if (e < N_EDGES) atomicAdd(&cnt[dst[e]], 1);
}

__global__ void k_count_batch(const int* __restrict__ batch, int* __restrict__ gcnt) {
    int v = blockIdx.x * 256 + threadIdx.x;
    if (v < N_NODES) atomicAdd(&gcnt[batch[v]], 1);
}

__global__ __launch_bounds__(256) void k_chunksum(const int* __restrict__ cnt,
                                                  int* __restrict__ csum) {
    int i = blockIdx.x * 256 + threadIdx.x;
    int v = (i < N_NODES) ? cnt[i] : 0;
#pragma unroll
    for (int off = 32; off; off >>= 1) v += __shfl_down(v, off, 64);
    __shared__ int ws[4];
    if ((threadIdx.x & 63) == 0) ws[threadIdx.x >> 6] = v;
    __syncthreads();
    if (threadIdx.x == 0) csum[blockIdx.x] = ws[0] + ws[1] + ws[2] + ws[3];
}

__global__ __launch_bounds__(256) void k_scanchunks(const int* __restrict__ csum,
                                                    int* __restrict__ choff) {
    __shared__ int s[256];
    int t = threadIdx.x;
    int v = (t < NCHUNK) ? csum[t] : 0;
    s[t] = v;
    __syncthreads();
#pragma unroll
    for (int off = 1; off < 256; off <<= 1) {
        int add = (t >= off) ? s[t - off] : 0;
        __syncthreads();
        s[t] += add;
        __syncthreads();
    }
    if (t < NCHUNK) choff[t] = s[t] - v;   // exclusive
}

__global__ __launch_bounds__(256) void k_apply(const int* __restrict__ cnt,
                                               const int* __restrict__ choff,
                                               int* __restrict__ rowp,
                                               int* __restrict__ cursor,
                                               float* __restrict__ dinv) {
    __shared__ int s[256];
    int t = threadIdx.x;
    int i = blockIdx.x * 256 + t;
    int c = (i < N_NODES) ? cnt[i] : 0;
    s[t] = c;
    __syncthreads();
#pragma unroll
    for (int off = 1; off < 256; off <<= 1) {
        int add = (t >= off) ? s[t - off] : 0;
        __syncthreads();
        s[t] += add;
        __syncthreads();
    }
    int incl = s[t];
    int base = choff[blockIdx.x];
    if (i < N_NODES) {
        int ex = base + incl - c;
        rowp[i] = ex;
        cursor[i] = ex;
        dinv[i] = rsqrtf(1.0f + (float)c);
        if (i == N_NODES - 1) rowp[N_NODES] = base + incl;
    }
}

__global__ void k_fill(const int* __restrict__ src, const int* __restrict__ dst,
                       int* __restrict__ cursor, int* __restrict__ col) {
    int e = blockIdx.x * 256 + threadIdx.x;
    if (e < N_EDGES) {
        int slot = atomicAdd(&cursor[dst[e]], 1);
        col[slot] = src[e];
    }
}

// ---------------- prescale: p0 = bf16(x * dinv[row]) ----------------
__global__ void k_prescale(const float* __restrict__ x, const float* __restrict__ dinv,
                           ushort* __restrict__ p0) {
    int i = blockIdx.x * 256 + threadIdx.x;      // per 4 elems
    if (i < N_NODES * IN_FEAT / 4) {
        float4 v = ((const float4*)x)[i];
        float d = dinv[i / (IN_FEAT / 4)];
        ushort4 o;
        o.x = f2bf(v.x * d); o.y = f2bf(v.y * d);
        o.z = f2bf(v.z * d); o.w = f2bf(v.w * d);
        ((ushort4*)p0)[i] = o;
    }
}

// ---------------- aggregation (bf16 rows, fp32 accum, 4-deep gather pipeline) ----------------
template <int F>
__global__ __launch_bounds__(256) void k_agg(const ushort* __restrict__ p,
                                             const int* __restrict__ col,
                                             const int* __restrict__ row_ptr,
                                             const float* __restrict__ dinv,
                                             ushort* __restrict__ out) {
    int wave = threadIdx.x >> 6;
    int lane = threadIdx.x & 63;
    int v = blockIdx.x * 4 + wave;
    if (v >= N_NODES) return;
    int rp0 = row_ptr[v], rp1 = row_ptr[v + 1];
    float d = dinv[v];
    if constexpr (F == 256) {
        ushort4 me = ((const ushort4*)(p + (size_t)v * F))[lane];
        float a0 = bf2f(me.x), a1 = bf2f(me.y), a2 = bf2f(me.z), a3 = bf2f(me.w);
        int i = rp0;
        for (; i + 4 <= rp1; i += 4) {
            int s0 = col[i], s1 = col[i + 1], s2 = col[i + 2], s3 = col[i + 3];
            ushort4 q0 = ((const ushort4*)(p + (size_t)s0 * F))[lane];
            ushort4 q1 = ((const ushort4*)(p + (size_t)s1 * F))[lane];
            ushort4 q2 = ((const ushort4*)(p + (size_t)s2 * F))[lane];
            ushort4 q3 = ((const ushort4*)(p + (size_t)s3 * F))[lane];
            a0 += bf2f(q0.x) + bf2f(q1.x) + bf2f(q2.x) + bf2f(q3.x);
            a1 += bf2f(q0.y) + bf2f(q1.y) + bf2f(q2.y) + bf2f(q3.y);
            a2 += bf2f(q0.z) + bf2f(q1.z) + bf2f(q2.z) + bf2f(q3.z);
            a3 += bf2f(q0.w) + bf2f(q1.w) + bf2f(q2.w) + bf2f(q3.w);
        }
        for (; i < rp1; ++i) {
            int s = col[i];
            ushort4 q = ((const ushort4*)(p + (size_t)s * F))[lane];
            a0 += bf2f(q.x); a1 += bf2f(q.y); a2 += bf2f(q.z); a3 += bf2f(q.w);
        }
        ushort4 o;
        o.x = f2bf(a0 * d); o.y = f2bf(a1 * d); o.z = f2bf(a2 * d); o.w = f2bf(a3 * d);
        ((ushort4*)(out + (size_t)v * F))[lane] = o;
    } else {
        ushort2 me = ((const ushort2*)(p + (size_t)v * F))[lane];
        float a0 = bf2f(me.x), a1 = bf2f(me.y);
        int i = rp0;
        for (; i + 4 <= rp1; i += 4) {
            int s0 = col[i], s1 = col[i + 1], s2 = col[i + 2], s3 = col[i + 3];
            ushort2 q0 = ((const ushort2*)(p + (size_t)s0 * F))[lane];
            ushort2 q1 = ((const ushort2*)(p + (size_t)s1 * F))[lane];
            ushort2 q2 = ((const ushort2*)(p + (size_t)s2 * F))[lane];
            ushort2 q3 = ((const ushort2*)(p + (size_t)s3 * F))[lane];
            a0 += bf2f(q0.x) + bf2f(q1.x) + bf2f(q2.x) + bf2f(q3.x);
            a1 += bf2f(q0.y) + bf2f(q1.y) + bf2f(q2.y) + bf2f(q3.y);
        }
        for (; i < rp1; ++i) {
            int s = col[i];
            ushort2 q = ((const ushort2*)(p + (size_t)s * F))[lane];
            a0 += bf2f(q.x); a1 += bf2f(q.y);
        }
        ushort2 o;
        o.x = f2bf(a0 * d); o.y = f2bf(a1 * d);
        ((ushort2*)(out + (size_t)v * F))[lane] = o;
    }
}

// ---------------- W repack: fp32 [K][256] -> bf16 frag layout [nt][kt][lane][8] ----------------
template <int KDIM>
__global__ void k_repackW(const float* __restrict__ W, ushort* __restrict__ Wp) {
    const int KT = KDIM / 32;
    int tid = blockIdx.x * 256 + threadIdx.x;
    if (tid >= 16 * KT * 64) return;
    int lane = tid & 63;
    int kt = (tid >> 6) % KT;
    int nt = (tid >> 6) / KT;
    int n = nt * 16 + (lane & 15);
    int kb = kt * 32 + (lane >> 4) * 8;
    ushort o[8];
#pragma unroll
    for (int j = 0; j < 8; ++j) o[j] = f2bf(W[(size_t)(kb + j) * HIDDEN + n]);
    ushort4* dst = (ushort4*)(Wp + (size_t)tid * 8);
    dst[0] = make_ushort4(o[0], o[1], o[2], o[3]);
    dst[1] = make_ushort4(o[4], o[5], o[6], o[7]);
}

// ---------------- MFMA GEMM: out = epi(A @ W + bias), bf16 in/out, fp32 acc ----------------
// EPI: 0 = BN+relu then *dinv ; 1 = relu then *dinv ; 2 = relu (plain)
template <int KDIM, int EPI>
__global__ __launch_bounds__(256) void k_mgemm(const ushort* __restrict__ A,
                                               const ushort* __restrict__ Wp,
                                               const float* __restrict__ bias,
                                               const float* __restrict__ gamma,
                                               const float* __restrict__ beta,
                                               const float* __restrict__ mean,
                                               const float* __restrict__ var,
                                               const float* __restrict__ dinv,
                                               ushort* __restrict__ out) {
    const int KT = KDIM / 32;
    int t = threadIdx.x;
    int wv = t >> 6, lane = t & 63;
    int row0 = blockIdx.x * 64 + wv * 16;
    int g = lane >> 4, r16 = lane & 15;
    int arow = row0 + r16;
    if (arow >= N_NODES) arow = N_NODES - 1;   // safe load; store guarded

    f32x4 acc[16];
#pragma unroll
    for (int nt = 0; nt < 16; ++nt) acc[nt] = (f32x4){0.f, 0.f, 0.f, 0.f};

    const ushort* aptr = A + (size_t)arow * KDIM + g * 8;
    for (int kt = 0; kt < KT; ++kt) {
        bf16x8 af = *(const bf16x8*)(aptr + kt * 32);
#pragma unroll
        for (int nt = 0; nt < 16; ++nt) {
            bf16x8 bfv = *(const bf16x8*)(Wp + ((size_t)(nt * KT + kt) * 64 + lane) * 8);
            acc[nt] = __builtin_amdgcn_mfma_f32_16x16x32_bf16(af, bfv, acc[nt], 0, 0, 0);
        }
    }

    // epilogue: lane covers rows row0+g*4+r (r=0..3), col nt*16+r16
    int rowb = row0 + g * 4;
    float dv[4];
#pragma unroll
    for (int r = 0; r < 4; ++r) {
        int grow = rowb + r;
        dv[r] = 1.f;
        if (EPI != 2 && grow < N_NODES) dv[r] = dinv[grow];
    }
#pragma unroll
    for (int nt = 0; nt < 16; ++nt) {
        int colc = nt * 16 + r16;
        float bi = bias[colc];
        float sc = 1.f, sh = 0.f;
        if constexpr (EPI == 0) {
            float s = gamma[colc] * rsqrtf(var[colc] + BN_EPS);
            sc = s; sh = beta[colc] - mean[colc] * s;
        }
#pragma unroll
        for (int r = 0; r < 4; ++r) {
            int grow = rowb + r;
            if (grow < N_NODES) {
                float y = acc[nt][r] + bi;
                if constexpr (EPI == 0) y = y * sc + sh;
                y = fmaxf(y, 0.f);
                y *= dv[r];
                out[(size_t)grow * HIDDEN + colc] = f2bf(y);
            }
        }
    }
}

// ---------------- pooling: sums[g][c] += h[v][c] (bf16 h, fp32 sums) ----------------
__global__ __launch_bounds__(256) void k_pool(const ushort* __restrict__ h,
                                              const int* __restrict__ batch,
                                              float* __restrict__ sums) {
    __shared__ float acc[NUM_GRAPHS][64];
    int slice = blockIdx.x % POOL_SLICES;
    int chunk = blockIdx.x / POOL_SLICES;
    int t = threadIdx.x;
    for (int i = t; i < NUM_GRAPHS * 64; i += 256) ((float*)acc)[i] = 0.f;
    __syncthreads();
    int lane = t & 63;
    int wv = t >> 6;
    const int per_chunk = (N_NODES + POOL_CHUNKS - 1) / POOL_CHUNKS;
    int v0 = chunk * per_chunk;
    int v1 = min(v0 + per_chunk, N_NODES);
    int c = slice * 64 + lane;
    for (int v = v0 + wv; v < v1; v += 4) {
        int g = batch[v];
        float val = bf2f(h[(size_t)v * HIDDEN + c]);
        atomicAdd(&acc[g][lane], val);
    }
    __syncthreads();
    for (int i = t; i < NUM_GRAPHS * 64; i += 256) {
        float val = ((float*)acc)[i];
        if (val != 0.f) atomicAdd(&sums[(size_t)(i >> 6) * HIDDEN + slice * 64 + (i & 63)], val);
    }
}

// ---------------- logits + log_softmax per graph ----------------
__global__ __launch_bounds__(256) void k_logits(const float* __restrict__ sums,
                                                const int* __restrict__ gcnt,
                                                const float* __restrict__ W2,
                                                const float* __restrict__ b2,
                                                float* __restrict__ outp) {
    __shared__ float pooled[HIDDEN];
    int g = blockIdx.x;
    int t = threadIdx.x;
    float inv = 1.0f / fmaxf((float)gcnt[g], 1.0f);
    pooled[t] = sums[(size_t)g * HIDDEN + t] * inv;
    __syncthreads();
    if (t < 64) {
        float lg = -INFINITY;
        if (t < NUM_CLASSES) {
            lg = b2[t];
            for (int k = 0; k < HIDDEN; ++k) lg += pooled[k] * W2[k * NUM_CLASSES + t];
        }
        float m = lg;
        for (int off = 1; off < 16; off <<= 1) m = fmaxf(m, __shfl_xor(m, off));
        float e = (t < 16) ? expf(lg - m) : 0.f;
        float ssum = e;
        for (int off = 1; off < 16; off <<= 1) ssum += __shfl_xor(ssum, off);
        if (t < NUM_CLASSES) outp[g * NUM_CLASSES + t] = lg - m - logf(ssum);
    }
}

extern "C" void kernel_launch(void* const* d_in, const int* in_sizes, int n_in,
                              void* d_out, int out_size, void* d_ws, size_t ws_size,
                              hipStream_t stream) {
    const float* x     = (const float*)d_in[0];
    const int*   ei    = (const int*)d_in[1];
    const int*   batch = (const int*)d_in[2];
    const float* W1    = (const float*)d_in[3];
    const float* b1    = (const float*)d_in[4];
    const float* gamma = (const float*)d_in[5];
    const float* beta  = (const float*)d_in[6];
    const float* rmean = (const float*)d_in[7];
    const float* rvar  = (const float*)d_in[8];
    const float* Wsp   = (const float*)d_in[9];
    const float* bsp   = (const float*)d_in[10];
    const float* W2    = (const float*)d_in[11];
    const float* b2    = (const float*)d_in[12];
    float* out = (float*)d_out;

    char* w = (char*)d_ws;
    size_t off = 0;
    auto alloc = [&](size_t bytes) -> void* {
        void* p = w + off;
        off = (off + bytes + 255) & ~(size_t)255;
        return p;
    };
    int*    cnt    = (int*)alloc((size_t)N_NODES * 4);
    int*    gcnt   = (int*)alloc((size_t)NUM_GRAPHS * 4);
    int*    rowp   = (int*)alloc((size_t)(N_NODES + 1) * 4);
    int*    cursor = (int*)alloc((size_t)N_NODES * 4);
    int*    col    = (int*)alloc((size_t)N_EDGES * 4);
    float*  dinv   = (float*)alloc((size_t)N_NODES * 4);
    int*    csum   = (int*)alloc((size_t)NCHUNK * 4);
    int*    choff  = (int*)alloc((size_t)NCHUNK * 4);
    float*  sums   = (float*)alloc((size_t)NUM_GRAPHS * HIDDEN * 4);
    ushort* Wp1    = (ushort*)alloc((size_t)16 * 4 * 64 * 8 * 2);
    ushort* Wp2    = (ushort*)alloc((size_t)16 * 8 * 64 * 8 * 2);
    ushort* Wp3    = (ushort*)alloc((size_t)16 * 8 * 64 * 8 * 2);
    ushort* Wp4    = (ushort*)alloc((size_t)16 * 8 * 64 * 8 * 2);
    ushort* bufA   = (ushort*)alloc((size_t)N_NODES * HIDDEN * 2);
    ushort* bufB   = (ushort*)alloc((size_t)N_NODES * HIDDEN * 2);

    hipMemsetAsync(cnt, 0, (size_t)N_NODES * 4, stream);
    hipMemsetAsync(gcnt, 0, (size_t)NUM_GRAPHS * 4, stream);
    hipMemsetAsync(sums, 0, (size_t)NUM_GRAPHS * HIDDEN * 4, stream);

    const int* srcp = ei;
    const int* dstp = ei + N_EDGES;

    // CSR + degree
    k_count<<<(N_EDGES + 255) / 256, 256, 0, stream>>>(dstp, cnt);
    k_count_batch<<<(N_NODES + 255) / 256, 256, 0, stream>>>(batch, gcnt);
    k_chunksum<<<NCHUNK, 256, 0, stream>>>(cnt, csum);
    k_scanchunks<<<1, 256, 0, stream>>>(csum, choff);
    k_apply<<<NCHUNK, 256, 0, stream>>>(cnt, choff, rowp, cursor, dinv);
    k_fill<<<(N_EDGES + 255) / 256, 256, 0, stream>>>(srcp, dstp, cursor, col);

    // weight repack (fp32 -> bf16 fragment layout)
    k_repackW<IN_FEAT><<<(16 * 4 * 64 + 255) / 256, 256, 0, stream>>>(W1, Wp1);
    k_repackW<HIDDEN><<<(16 * 8 * 64 + 255) / 256, 256, 0, stream>>>(Wsp + 0 * HIDDEN * HIDDEN, Wp2);
    k_repackW<HIDDEN><<<(16 * 8 * 64 + 255) / 256, 256, 0, stream>>>(Wsp + 1 * HIDDEN * HIDDEN, Wp3);
    k_repackW<HIDDEN><<<(16 * 8 * 64 + 255) / 256, 256, 0, stream>>>(Wsp + 2 * HIDDEN * HIDDEN, Wp4);

    const int GG = (N_NODES + 63) / 64;

    // layer 1
    k_prescale<<<(N_NODES * IN_FEAT / 4 + 255) / 256, 256, 0, stream>>>(x, dinv, bufA);
    k_agg<IN_FEAT><<<(N_NODES + 3) / 4, 256, 0, stream>>>(bufA, col, rowp, dinv, bufB);
    k_mgemm<IN_FEAT, 0><<<GG, 256, 0, stream>>>(bufB, Wp1, b1, gamma, beta, rmean, rvar, dinv, bufA);

    // layers 2..3
    k_agg<HIDDEN><<<(N_NODES + 3) / 4, 256, 0, stream>>>(bufA, col, rowp, dinv, bufB);
    k_mgemm<HIDDEN, 1><<<GG, 256, 0, stream>>>(bufB, Wp2, bsp + 0 * HIDDEN,
                                               nullptr, nullptr, nullptr, nullptr, dinv, bufA);

    k_agg<HIDDEN><<<(N_NODES + 3) / 4, 256, 0, stream>>>(bufA, col, rowp, dinv, bufB);
    k_mgemm<HIDDEN, 1><<<GG, 256, 0, stream>>>(bufB, Wp3, bsp + 1 * HIDDEN,
                                               nullptr, nullptr, nullptr, nullptr, dinv, bufA);

    // layer 4 (plain relu, feeds pooling)
    k_agg<HIDDEN><<<(N_NODES + 3) / 4, 256, 0, stream>>>(bufA, col, rowp, dinv, bufB);
    k_mgemm<HIDDEN, 2><<<GG, 256, 0, stream>>>(bufB, Wp4, bsp + 2 * HIDDEN,
                                               nullptr, nullptr, nullptr, nullptr, dinv, bufA);

    k_pool<<<POOL_CHUNKS * POOL_SLICES, 256, 0, stream>>>(bufA, batch, sums);
    k_logits<<<NUM_GRAPHS, 256, 0, stream>>>(sums, gcnt, W2, b2, out);
}

// Round 6
// 622.148 us; speedup vs baseline: 4.0773x; 1.0138x over previous
//
#include <hip/hip_runtime.h>
#include <math.h>

#define N_NODES 50000
#define N_EDGES 800000
#define IN_FEAT 128
#define HIDDEN 256
#define NUM_GRAPHS 128
#define NUM_CLASSES 10
#define BN_EPS 1e-5f

#define NCHUNK ((N_NODES + 255) / 256)   // 196 scan chunks

typedef __attribute__((ext_vector_type(8))) short bf16x8;
typedef __attribute__((ext_vector_type(4))) float f32x4;

__device__ __forceinline__ ushort f2bf(float f) {
    union { float f; uint u; } c; c.f = f;
    uint u = c.u;
    return (ushort)((u + 0x7FFFu + ((u >> 16) & 1u)) >> 16);   // RNE
}
__device__ __forceinline__ float bf2f(ushort h) {
    union { uint u; float f; } c; c.u = ((uint)h) << 16;
    return c.f;
}

// ---------------- CSR build ----------------
__global__ void k_count(const int* __restrict__ dst, int* __restrict__ cnt) {
    int e = blockIdx.x * 256 + threadIdx.x;
    if (e < N_EDGES) atomicAdd(&cnt[dst[e]], 1);
}

__global__ void k_count_batch(const int* __restrict__ batch, int* __restrict__ gcnt) {
    int v = blockIdx.x * 256 + threadIdx.x;
    if (v < N_NODES) atomicAdd(&gcnt[batch[v]], 1);
}

__global__ __launch_bounds__(256) void k_chunksum(const int* __restrict__ cnt,
                                                  int* __restrict__ csum) {
    int i = blockIdx.x * 256 + threadIdx.x;
    int v = (i < N_NODES) ? cnt[i] : 0;
#pragma unroll
    for (int off = 32; off; off >>= 1) v += __shfl_down(v, off, 64);
    __shared__ int ws[4];
    if ((threadIdx.x & 63) == 0) ws[threadIdx.x >> 6] = v;
    __syncthreads();
    if (threadIdx.x == 0) csum[blockIdx.x] = ws[0] + ws[1] + ws[2] + ws[3];
}

__global__ __launch_bounds__(256) void k_scanchunks(const int* __restrict__ csum,
                                                    int* __restrict__ choff) {
    __shared__ int s[256];
    int t = threadIdx.x;
    int v = (t < NCHUNK) ? csum[t] : 0;
    s[t] = v;
    __syncthreads();
#pragma unroll
    for (int off = 1; off < 256; off <<= 1) {
        int add = (t >= off) ? s[t - off] : 0;
        __syncthreads();
        s[t] += add;
        __syncthreads();
    }
    if (t < NCHUNK) choff[t] = s[t] - v;   // exclusive
}

__global__ __launch_bounds__(256) void k_apply(const int* __restrict__ cnt,
                                               const int* __restrict__ choff,
                                               int* __restrict__ rowp,
                                               int* __restrict__ cursor,
                                               float* __restrict__ dinv) {
    __shared__ int s[256];
    int t = threadIdx.x;
    int i = blockIdx.x * 256 + t;
    int c = (i < N_NODES) ? cnt[i] : 0;
    s[t] = c;
    __syncthreads();
#pragma unroll
    for (int off = 1; off < 256; off <<= 1) {
        int add = (t >= off) ? s[t - off] : 0;
        __syncthreads();
        s[t] += add;
        __syncthreads();
    }
    int incl = s[t];
    int base = choff[blockIdx.x];
    if (i < N_NODES) {
        int ex = base + incl - c;
        rowp[i] = ex;
        cursor[i] = ex;
        dinv[i] = rsqrtf(1.0f + (float)c);
        if (i == N_NODES - 1) rowp[N_NODES] = base + incl;
    }
}

__global__ void k_fill(const int* __restrict__ src, const int* __restrict__ dst,
                       int* __restrict__ cursor, int* __restrict__ col) {
    int e = blockIdx.x * 256 + threadIdx.x;
    if (e < N_EDGES) {
        int slot = atomicAdd(&cursor[dst[e]], 1);
        col[slot] = src[e];
    }
}

// ---- graph bucketing for pooling: scan gcnt -> goff; fill nlist ----
__global__ void k_scangraphs(const int* __restrict__ gcnt, int* __restrict__ goff,
                             int* __restrict__ gcur) {
    __shared__ int s[NUM_GRAPHS];
    int t = threadIdx.x;                 // 128 threads
    int v = gcnt[t];
    s[t] = v;
    __syncthreads();
#pragma unroll
    for (int off = 1; off < NUM_GRAPHS; off <<= 1) {
        int add = (t >= off) ? s[t - off] : 0;
        __syncthreads();
        s[t] += add;
        __syncthreads();
    }
    goff[t] = s[t] - v;
    gcur[t] = s[t] - v;
    if (t == NUM_GRAPHS - 1) goff[NUM_GRAPHS] = s[t];
}

__global__ void k_fillg(const int* __restrict__ batch, int* __restrict__ gcur,
                        int* __restrict__ nlist) {
    int v = blockIdx.x * 256 + threadIdx.x;
    if (v < N_NODES) {
        int slot = atomicAdd(&gcur[batch[v]], 1);
        nlist[slot] = v;
    }
}

// ---------------- prescale: p0 = bf16(x * dinv[row]) ----------------
__global__ void k_prescale(const float* __restrict__ x, const float* __restrict__ dinv,
                           ushort* __restrict__ p0) {
    int i = blockIdx.x * 256 + threadIdx.x;      // per 4 elems
    if (i < N_NODES * IN_FEAT / 4) {
        float4 v = ((const float4*)x)[i];
        float d = dinv[i / (IN_FEAT / 4)];
        ushort4 o;
        o.x = f2bf(v.x * d); o.y = f2bf(v.y * d);
        o.z = f2bf(v.z * d); o.w = f2bf(v.w * d);
        ((ushort4*)p0)[i] = o;
    }
}

// ---------------- aggregation (bf16 rows, fp32 accum, 4-deep gather pipeline) ----------------
template <int F>
__global__ __launch_bounds__(256) void k_agg(const ushort* __restrict__ p,
                                             const int* __restrict__ col,
                                             const int* __restrict__ row_ptr,
                                             const float* __restrict__ dinv,
                                             ushort* __restrict__ out) {
    int wave = threadIdx.x >> 6;
    int lane = threadIdx.x & 63;
    int v = blockIdx.x * 4 + wave;
    if (v >= N_NODES) return;
    int rp0 = row_ptr[v], rp1 = row_ptr[v + 1];
    float d = dinv[v];
    if constexpr (F == 256) {
        ushort4 me = ((const ushort4*)(p + (size_t)v * F))[lane];
        float a0 = bf2f(me.x), a1 = bf2f(me.y), a2 = bf2f(me.z), a3 = bf2f(me.w);
        int i = rp0;
        for (; i + 4 <= rp1; i += 4) {
            int s0 = col[i], s1 = col[i + 1], s2 = col[i + 2], s3 = col[i + 3];
            ushort4 q0 = ((const ushort4*)(p + (size_t)s0 * F))[lane];
            ushort4 q1 = ((const ushort4*)(p + (size_t)s1 * F))[lane];
            ushort4 q2 = ((const ushort4*)(p + (size_t)s2 * F))[lane];
            ushort4 q3 = ((const ushort4*)(p + (size_t)s3 * F))[lane];
            a0 += bf2f(q0.x) + bf2f(q1.x) + bf2f(q2.x) + bf2f(q3.x);
            a1 += bf2f(q0.y) + bf2f(q1.y) + bf2f(q2.y) + bf2f(q3.y);
            a2 += bf2f(q0.z) + bf2f(q1.z) + bf2f(q2.z) + bf2f(q3.z);
            a3 += bf2f(q0.w) + bf2f(q1.w) + bf2f(q2.w) + bf2f(q3.w);
        }
        for (; i < rp1; ++i) {
            int s = col[i];
            ushort4 q = ((const ushort4*)(p + (size_t)s * F))[lane];
            a0 += bf2f(q.x); a1 += bf2f(q.y); a2 += bf2f(q.z); a3 += bf2f(q.w);
        }
        ushort4 o;
        o.x = f2bf(a0 * d); o.y = f2bf(a1 * d); o.z = f2bf(a2 * d); o.w = f2bf(a3 * d);
        ((ushort4*)(out + (size_t)v * F))[lane] = o;
    } else {
        ushort2 me = ((const ushort2*)(p + (size_t)v * F))[lane];
        float a0 = bf2f(me.x), a1 = bf2f(me.y);
        int i = rp0;
        for (; i + 4 <= rp1; i += 4) {
            int s0 = col[i], s1 = col[i + 1], s2 = col[i + 2], s3 = col[i + 3];
            ushort2 q0 = ((const ushort2*)(p + (size_t)s0 * F))[lane];
            ushort2 q1 = ((const ushort2*)(p + (size_t)s1 * F))[lane];
            ushort2 q2 = ((const ushort2*)(p + (size_t)s2 * F))[lane];
            ushort2 q3 = ((const ushort2*)(p + (size_t)s3 * F))[lane];
            a0 += bf2f(q0.x) + bf2f(q1.x) + bf2f(q2.x) + bf2f(q3.x);
            a1 += bf2f(q0.y) + bf2f(q1.y) + bf2f(q2.y) + bf2f(q3.y);
        }
        for (; i < rp1; ++i) {
            int s = col[i];
            ushort2 q = ((const ushort2*)(p + (size_t)s * F))[lane];
            a0 += bf2f(q.x); a1 += bf2f(q.y);
        }
        ushort2 o;
        o.x = f2bf(a0 * d); o.y = f2bf(a1 * d);
        ((ushort2*)(out + (size_t)v * F))[lane] = o;
    }
}

// ---------------- W repack: fp32 [K][256] -> bf16 frag layout [nt][kt][lane][8] ----------------
template <int KDIM>
__global__ void k_repackW(const float* __restrict__ W, ushort* __restrict__ Wp) {
    const int KT = KDIM / 32;
    int tid = blockIdx.x * 256 + threadIdx.x;
    if (tid >= 16 * KT * 64) return;
    int lane = tid & 63;
    int kt = (tid >> 6) % KT;
    int nt = (tid >> 6) / KT;
    int n = nt * 16 + (lane & 15);
    int kb = kt * 32 + (lane >> 4) * 8;
    ushort o[8];
#pragma unroll
    for (int j = 0; j < 8; ++j) o[j] = f2bf(W[(size_t)(kb + j) * HIDDEN + n]);
    ushort4* dst = (ushort4*)(Wp + (size_t)tid * 8);
    dst[0] = make_ushort4(o[0], o[1], o[2], o[3]);
    dst[1] = make_ushort4(o[4], o[5], o[6], o[7]);
}

// ---------------- MFMA GEMM: out = epi(A @ W + bias), bf16 in/out, fp32 acc ----------------
// EPI: 0 = BN+relu then *dinv ; 1 = relu then *dinv ; 2 = relu (plain)
template <int KDIM, int EPI>
__global__ __launch_bounds__(256) void k_mgemm(const ushort* __restrict__ A,
                                               const ushort* __restrict__ Wp,
                                               const float* __restrict__ bias,
                                               const float* __restrict__ gamma,
                                               const float* __restrict__ beta,
                                               const float* __restrict__ mean,
                                               const float* __restrict__ var,
                                               const float* __restrict__ dinv,
                                               ushort* __restrict__ out) {
    const int KT = KDIM / 32;
    int t = threadIdx.x;
    int wv = t >> 6, lane = t & 63;
    int row0 = blockIdx.x * 64 + wv * 16;
    int g = lane >> 4, r16 = lane & 15;
    int arow = row0 + r16;
    if (arow >= N_NODES) arow = N_NODES - 1;   // safe load; store guarded

    f32x4 acc[16];
#pragma unroll
    for (int nt = 0; nt < 16; ++nt) acc[nt] = (f32x4){0.f, 0.f, 0.f, 0.f};

    const ushort* aptr = A + (size_t)arow * KDIM + g * 8;
    for (int kt = 0; kt < KT; ++kt) {
        bf16x8 af = *(const bf16x8*)(aptr + kt * 32);
#pragma unroll
        for (int nt = 0; nt < 16; ++nt) {
            bf16x8 bfv = *(const bf16x8*)(Wp + ((size_t)(nt * KT + kt) * 64 + lane) * 8);
            acc[nt] = __builtin_amdgcn_mfma_f32_16x16x32_bf16(af, bfv, acc[nt], 0, 0, 0);
        }
    }

    // epilogue: lane covers rows row0+g*4+r (r=0..3), col nt*16+r16
    int rowb = row0 + g * 4;
    float dv[4];
#pragma unroll
    for (int r = 0; r < 4; ++r) {
        int grow = rowb + r;
        dv[r] = 1.f;
        if (EPI != 2 && grow < N_NODES) dv[r] = dinv[grow];
    }
#pragma unroll
    for (int nt = 0; nt < 16; ++nt) {
        int colc = nt * 16 + r16;
        float bi = bias[colc];
        float sc = 1.f, sh = 0.f;
        if constexpr (EPI == 0) {
            float s = gamma[colc] * rsqrtf(var[colc] + BN_EPS);
            sc = s; sh = beta[colc] - mean[colc] * s;
        }
#pragma unroll
        for (int r = 0; r < 4; ++r) {
            int grow = rowb + r;
            if (grow < N_NODES) {
                float y = acc[nt][r] + bi;
                if constexpr (EPI == 0) y = y * sc + sh;
                y = fmaxf(y, 0.f);
                y *= dv[r];
                out[(size_t)grow * HIDDEN + colc] = f2bf(y);
            }
        }
    }
}

// ---------------- pooling: segment-sum over graph-sorted node list ----------------
// grid = NUM_GRAPHS * 2 (col halves); block = 4 waves; lane owns 2 cols.
__global__ __launch_bounds__(256) void k_pool2(const ushort* __restrict__ h,
                                               const int* __restrict__ nlist,
                                               const int* __restrict__ goff,
                                               float* __restrict__ sums) {
    int g = blockIdx.x >> 1, half = blockIdx.x & 1;
    int lo = goff[g], hi = goff[g + 1];
    int w = threadIdx.x >> 6, l = threadIdx.x & 63;
    const ushort* hp = h + half * 128 + l * 2;
    float a0 = 0.f, a1 = 0.f;
    int i = lo + w;
    for (; i + 12 < hi; i += 16) {
        int v0 = nlist[i], v1 = nlist[i + 4], v2 = nlist[i + 8], v3 = nlist[i + 12];
        ushort2 q0 = *(const ushort2*)(hp + (size_t)v0 * HIDDEN);
        ushort2 q1 = *(const ushort2*)(hp + (size_t)v1 * HIDDEN);
        ushort2 q2 = *(const ushort2*)(hp + (size_t)v2 * HIDDEN);
        ushort2 q3 = *(const ushort2*)(hp + (size_t)v3 * HIDDEN);
        a0 += bf2f(q0.x) + bf2f(q1.x) + bf2f(q2.x) + bf2f(q3.x);
        a1 += bf2f(q0.y) + bf2f(q1.y) + bf2f(q2.y) + bf2f(q3.y);
    }
    for (; i < hi; i += 4) {
        int v = nlist[i];
        ushort2 q = *(const ushort2*)(hp + (size_t)v * HIDDEN);
        a0 += bf2f(q.x); a1 += bf2f(q.y);
    }
    __shared__ float red[4][128];
    red[w][l * 2] = a0;
    red[w][l * 2 + 1] = a1;
    __syncthreads();
    int t = threadIdx.x;
    if (t < 128) {
        float s = red[0][t] + red[1][t] + red[2][t] + red[3][t];
        sums[(size_t)g * HIDDEN + half * 128 + t] = s;
    }
}

// ---------------- logits + log_softmax per graph ----------------
__global__ __launch_bounds__(256) void k_logits(const float* __restrict__ sums,
                                                const int* __restrict__ gcnt,
                                                const float* __restrict__ W2,
                                                const float* __restrict__ b2,
                                                float* __restrict__ outp) {
    __shared__ float pooled[HIDDEN];
    int g = blockIdx.x;
    int t = threadIdx.x;
    float inv = 1.0f / fmaxf((float)gcnt[g], 1.0f);
    pooled[t] = sums[(size_t)g * HIDDEN + t] * inv;
    __syncthreads();
    if (t < 64) {
        float lg = -INFINITY;
        if (t < NUM_CLASSES) {
            lg = b2[t];
            for (int k = 0; k < HIDDEN; ++k) lg += pooled[k] * W2[k * NUM_CLASSES + t];
        }
        float m = lg;
        for (int off = 1; off < 16; off <<= 1) m = fmaxf(m, __shfl_xor(m, off));
        float e = (t < 16) ? expf(lg - m) : 0.f;
        float ssum = e;
        for (int off = 1; off < 16; off <<= 1) ssum += __shfl_xor(ssum, off);
        if (t < NUM_CLASSES) outp[g * NUM_CLASSES + t] = lg - m - logf(ssum);
    }
}

extern "C" void kernel_launch(void* const* d_in, const int* in_sizes, int n_in,
                              void* d_out, int out_size, void* d_ws, size_t ws_size,
                              hipStream_t stream) {
    const float* x     = (const float*)d_in[0];
    const int*   ei    = (const int*)d_in[1];
    const int*   batch = (const int*)d_in[2];
    const float* W1    = (const float*)d_in[3];
    const float* b1    = (const float*)d_in[4];
    const float* gamma = (const float*)d_in[5];
    const float* beta  = (const float*)d_in[6];
    const float* rmean = (const float*)d_in[7];
    const float* rvar  = (const float*)d_in[8];
    const float* Wsp   = (const float*)d_in[9];
    const float* bsp   = (const float*)d_in[10];
    const float* W2    = (const float*)d_in[11];
    const float* b2    = (const float*)d_in[12];
    float* out = (float*)d_out;

    char* w = (char*)d_ws;
    size_t off = 0;
    auto alloc = [&](size_t bytes) -> void* {
        void* p = w + off;
        off = (off + bytes + 255) & ~(size_t)255;
        return p;
    };
    int*    cnt    = (int*)alloc((size_t)N_NODES * 4);
    int*    gcnt   = (int*)alloc((size_t)NUM_GRAPHS * 4);
    int*    rowp   = (int*)alloc((size_t)(N_NODES + 1) * 4);
    int*    cursor = (int*)alloc((size_t)N_NODES * 4);
    int*    col    = (int*)alloc((size_t)N_EDGES * 4);
    float*  dinv   = (float*)alloc((size_t)N_NODES * 4);
    int*    csum   = (int*)alloc((size_t)NCHUNK * 4);
    int*    choff  = (int*)alloc((size_t)NCHUNK * 4);
    int*    goff   = (int*)alloc((size_t)(NUM_GRAPHS + 1) * 4);
    int*    gcur   = (int*)alloc((size_t)NUM_GRAPHS * 4);
    int*    nlist  = (int*)alloc((size_t)N_NODES * 4);
    float*  sums   = (float*)alloc((size_t)NUM_GRAPHS * HIDDEN * 4);
    ushort* Wp1    = (ushort*)alloc((size_t)16 * 4 * 64 * 8 * 2);
    ushort* Wp2    = (ushort*)alloc((size_t)16 * 8 * 64 * 8 * 2);
    ushort* Wp3    = (ushort*)alloc((size_t)16 * 8 * 64 * 8 * 2);
    ushort* Wp4    = (ushort*)alloc((size_t)16 * 8 * 64 * 8 * 2);
    ushort* bufA   = (ushort*)alloc((size_t)N_NODES * HIDDEN * 2);
    ushort* bufB   = (ushort*)alloc((size_t)N_NODES * HIDDEN * 2);

    hipMemsetAsync(cnt, 0, (size_t)N_NODES * 4, stream);
    hipMemsetAsync(gcnt, 0, (size_t)NUM_GRAPHS * 4, stream);

    const int* srcp = ei;
    const int* dstp = ei + N_EDGES;

    // CSR + degree + graph buckets
    k_count<<<(N_EDGES + 255) / 256, 256, 0, stream>>>(dstp, cnt);
    k_count_batch<<<(N_NODES + 255) / 256, 256, 0, stream>>>(batch, gcnt);
    k_chunksum<<<NCHUNK, 256, 0, stream>>>(cnt, csum);
    k_scanchunks<<<1, 256, 0, stream>>>(csum, choff);
    k_apply<<<NCHUNK, 256, 0, stream>>>(cnt, choff, rowp, cursor, dinv);
    k_fill<<<(N_EDGES + 255) / 256, 256, 0, stream>>>(srcp, dstp, cursor, col);
    k_scangraphs<<<1, NUM_GRAPHS, 0, stream>>>(gcnt, goff, gcur);
    k_fillg<<<(N_NODES + 255) / 256, 256, 0, stream>>>(batch, gcur, nlist);

    // weight repack (fp32 -> bf16 fragment layout)
    k_repackW<IN_FEAT><<<(16 * 4 * 64 + 255) / 256, 256, 0, stream>>>(W1, Wp1);
    k_repackW<HIDDEN><<<(16 * 8 * 64 + 255) / 256, 256, 0, stream>>>(Wsp + 0 * HIDDEN * HIDDEN, Wp2);
    k_repackW<HIDDEN><<<(16 * 8 * 64 + 255) / 256, 256, 0, stream>>>(Wsp + 1 * HIDDEN * HIDDEN, Wp3);
    k_repackW<HIDDEN><<<(16 * 8 * 64 + 255) / 256, 256, 0, stream>>>(Wsp + 2 * HIDDEN * HIDDEN, Wp4);

    const int GG = (N_NODES + 63) / 64;

    // layer 1
    k_prescale<<<(N_NODES * IN_FEAT / 4 + 255) / 256, 256, 0, stream>>>(x, dinv, bufA);
    k_agg<IN_FEAT><<<(N_NODES + 3) / 4, 256, 0, stream>>>(bufA, col, rowp, dinv, bufB);
    k_mgemm<IN_FEAT, 0><<<GG, 256, 0, stream>>>(bufB, Wp1, b1, gamma, beta, rmean, rvar, dinv, bufA);

    // layers 2..3
    k_agg<HIDDEN><<<(N_NODES + 3) / 4, 256, 0, stream>>>(bufA, col, rowp, dinv, bufB);
    k_mgemm<HIDDEN, 1><<<GG, 256, 0, stream>>>(bufB, Wp2, bsp + 0 * HIDDEN,
                                               nullptr, nullptr, nullptr, nullptr, dinv, bufA);

    k_agg<HIDDEN><<<(N_NODES + 3) / 4, 256, 0, stream>>>(bufA, col, rowp, dinv, bufB);
    k_mgemm<HIDDEN, 1><<<GG, 256, 0, stream>>>(bufB, Wp3, bsp + 1 * HIDDEN,
                                               nullptr, nullptr, nullptr, nullptr, dinv, bufA);

    // layer 4 (plain relu, feeds pooling)
    k_agg<HIDDEN><<<(N_NODES + 3) / 4, 256, 0, stream>>>(bufA, col, rowp, dinv, bufB);
    k_mgemm<HIDDEN, 2><<<GG, 256, 0, stream>>>(bufB, Wp4, bsp + 2 * HIDDEN,
                                               nullptr, nullptr, nullptr, nullptr, dinv, bufA);

    k_pool2<<<NUM_GRAPHS * 2, 256, 0, stream>>>(bufA, nlist, goff, sums);
    k_logits<<<NUM_GRAPHS, 256, 0, stream>>>(sums, gcnt, W2, b2, out);
}